// Round 13
// baseline (826.636 us; speedup 1.0000x reference)
//
#include <hip/hip_runtime.h>
#include <hip/hip_bf16.h>

#define NN 50000
#define NE 800000
#define NG 512
#define DD 128
#define MM 256
#define TT 4
#define NPASS 4
#define GHID 256
#define NKEY (NN * TT)          // CSR keys: src*4 + type

typedef __bf16 bf16x2 __attribute__((ext_vector_type(2)));
typedef __bf16 bf16x4 __attribute__((ext_vector_type(4)));
typedef __bf16 bf16x8 __attribute__((ext_vector_type(8)));
typedef float f32x4 __attribute__((ext_vector_type(4)));

__device__ __forceinline__ float fast_sigmoid(float x) {
    return __builtin_amdgcn_rcpf(1.f + __expf(-x));
}
__device__ __forceinline__ float fast_tanh(float x) {
    float e2 = __expf(2.f * x);
    return 1.f - 2.f * __builtin_amdgcn_rcpf(e2 + 1.f);
}

#define GLDS(SRC, DST) \
    __builtin_amdgcn_global_load_lds( \
        (const __attribute__((address_space(1))) unsigned int*)(SRC), \
        (__attribute__((address_space(3))) unsigned int*)(DST), 16, 0, 0)

// ================= setup: swizzled weights =================
__global__ void build_WK(const float* __restrict__ W_msg, __bf16* __restrict__ WK) {
    int i = blockIdx.x * 256 + threadIdx.x;           // 131072
    if (i >= 16 * 4 * 256 * 8) return;
    int j = i & 7, col = (i >> 3) & 255, g = i >> 11; // g=c*4+lq
    int k = g * 8 + j;
    WK[i] = (__bf16)W_msg[k * 256 + col];
}

// j-major GRU weight layout: WBj[j][c][lq][gate][lm][e]
// value = B[k=(c*4+lq)*8+e][col = gate*128 + j*16 + lm]
// K rows 0..255 (msgs) are permuted by pi to match the swapped-phase-A
// register layout: slot k holds msg column pi_inv(k).
__global__ void build_WBj(const float* __restrict__ W_ih, const float* __restrict__ W_hh,
                          __bf16* __restrict__ WB) {
    int i = blockIdx.x * 256 + threadIdx.x;           // 196608
    if (i >= 8 * 12 * 4 * 4 * 16 * 8) return;
    int low = i & 127;
    int lm = low >> 3, e = low & 7;
    int rest = i >> 7;
    int g  = rest & 3;
    int lq = (rest >> 2) & 3;
    int jc = rest >> 4;          // j*12 + c
    int c  = jc % 12;
    int j  = jc / 12;
    int k   = (c * 4 + lq) * 8 + e;     // 0..383
    int col = g * 128 + j * 16 + lm;    // 0..511
    int korig = k;
    if (k < 256) {                      // pi_inv: k=(c2,lq2,e2) -> col=nt*16+lq2*4+i2
        int c2 = k >> 5, lq2 = (k >> 3) & 3, e2 = k & 7;
        int nt = c2 * 2 + (e2 >> 2), i2 = e2 & 3;
        korig = nt * 16 + lq2 * 4 + i2;
    }
    float v = 0.f;
    if (col < 256) {
        v = (k < 256) ? W_ih[col * 256 + korig] : W_hh[col * 128 + (k - 256)];
    } else if (col < 384) {
        if (k < 256) v = W_ih[col * 256 + korig];
    } else {
        if (k >= 256) v = W_hh[(col - 128) * 128 + (k - 256)];
    }
    WB[i] = (__bf16)v;
}

__global__ void build_bias512(const float* __restrict__ b_ih, const float* __restrict__ b_hh,
                              float* __restrict__ b512) {
    int c = blockIdx.x * 256 + threadIdx.x;
    if (c >= 512) return;
    float v;
    if (c < 256) v = b_ih[c] + b_hh[c];
    else if (c < 384) v = b_ih[c];
    else v = b_hh[c - 128];
    b512[c] = v;
}

// ================= embedding =================
__global__ void embed_kernel(const int* __restrict__ node_types,
                             const float* __restrict__ emb,
                             float* __restrict__ hf, __bf16* __restrict__ hbc) {
    int t = blockIdx.x * 256 + threadIdx.x;
    if (t >= NN * DD) return;
    int node = t >> 7;
    float v = emb[node_types[node] * DD + (t & 127)];
    hf[t] = v;
    hbc[t] = (__bf16)v;
}

// ================= CSR build (keyed by src*4+type) =================
__global__ void hist_kernel(const int* __restrict__ src, const int* __restrict__ et,
                            int* __restrict__ counts) {
    int e = blockIdx.x * 256 + threadIdx.x;
    if (e < NE) atomicAdd(&counts[src[e] * TT + et[e]], 1);
}

__global__ void ghist_kernel(const int* __restrict__ n2g, int* __restrict__ gcounts) {
    int i = blockIdx.x * 256 + threadIdx.x;
    if (i < NN) atomicAdd(&gcounts[n2g[i]], 1);
}

__global__ void scan1(const int* __restrict__ counts, int* __restrict__ offsets,
                      int* __restrict__ bsum, int n) {
    __shared__ int sm[256];
    int i = blockIdx.x * 256 + threadIdx.x;
    int v = (i < n) ? counts[i] : 0;
    sm[threadIdx.x] = v;
    __syncthreads();
    for (int off = 1; off < 256; off <<= 1) {
        int t = (threadIdx.x >= off) ? sm[threadIdx.x - off] : 0;
        __syncthreads();
        sm[threadIdx.x] += t;
        __syncthreads();
    }
    if (i < n) offsets[i] = sm[threadIdx.x] - v;
    if (threadIdx.x == 255) bsum[blockIdx.x] = sm[255];
}

__global__ void scan2(int* __restrict__ bsum, int nb, int* __restrict__ offsets, int n) {
    __shared__ int sm[1024];
    int v = (threadIdx.x < nb) ? bsum[threadIdx.x] : 0;
    sm[threadIdx.x] = v;
    __syncthreads();
    for (int off = 1; off < 1024; off <<= 1) {
        int t = (threadIdx.x >= off) ? sm[threadIdx.x - off] : 0;
        __syncthreads();
        sm[threadIdx.x] += t;
        __syncthreads();
    }
    if (threadIdx.x < nb) bsum[threadIdx.x] = sm[threadIdx.x] - v;
    if (threadIdx.x == 1023) offsets[n] = sm[1023];
}

__global__ void scan3(int* __restrict__ offsets, const int* __restrict__ bsum,
                      int* __restrict__ cursor, int n) {
    int i = blockIdx.x * 256 + threadIdx.x;
    if (i < n) {
        int o = offsets[i] + bsum[blockIdx.x];
        offsets[i] = o;
        if (cursor) cursor[i] = o;
    }
}

__global__ void fill_kernel(const int* __restrict__ src, const int* __restrict__ dst,
                            const int* __restrict__ et, int* __restrict__ cursor,
                            int* __restrict__ elist) {
    int e = blockIdx.x * 256 + threadIdx.x;
    if (e >= NE) return;
    int pos = atomicAdd(&cursor[src[e] * TT + et[e]], 1);
    elist[pos] = dst[e];
}

// ================= FUSED agg + msgs GEMM + GRU GEMM =================
// Prologue: each wave aggregates ITS 16 rows (R9 row-per-wave body) into the
// block's X slice (L2-hot). Phase A (swapped-operand msgs GEMM) reads it back
// as A-fragments; phase B = GRU. 8 waves, 48 KB LDS.
__global__ __launch_bounds__(512, 4)
void msgs_gru(const int* __restrict__ offsets, const int* __restrict__ elist,
              __bf16* __restrict__ X, const __bf16* __restrict__ WK,
              const float* __restrict__ b_msg,
              const __bf16* __restrict__ WBj, const float* __restrict__ b512,
              float* __restrict__ hf, __bf16* __restrict__ hbc) {
    __shared__ __bf16 Bs[2][12288];   // 48 KB total
    int tid = threadIdx.x, wave = tid >> 6, lane = tid & 63;
    int lm = lane & 15, lq = lane >> 4;
    int r0 = blockIdx.x * 128 + wave * 16;
    int arow = r0 + lm; if (arow >= NN) arow = NN - 1;

    // ---------------- agg prologue: this wave's 16 rows ----------------
    {
        const __bf16* hb = hbc + lane * 2;
#pragma unroll 1
        for (int kk = 0; kk < 16; ++kk) {
            int row = r0 + kk;
            if (row >= NN) break;                      // wave-uniform
            int ob = row * TT;
            int o0 = __builtin_amdgcn_readfirstlane(offsets[ob]);
            int o1 = __builtin_amdgcn_readfirstlane(offsets[ob + 1]);
            int o2 = __builtin_amdgcn_readfirstlane(offsets[ob + 2]);
            int o3 = __builtin_amdgcn_readfirstlane(offsets[ob + 3]);
            int o4 = __builtin_amdgcn_readfirstlane(offsets[ob + 4]);
            int begs[4] = {o0, o1, o2, o3};
            int ends[4] = {o1, o2, o3, o4};
            float ax[4] = {0.f, 0.f, 0.f, 0.f};
            float ay[4] = {0.f, 0.f, 0.f, 0.f};

            bf16x2 v[4][8];
            int nb[4];
#pragma unroll
            for (int t = 0; t < 4; ++t) {
                int beg = begs[t], end = ends[t];
                nb[t] = end - beg;
                int e1 = end - 1;
                if (e1 < 0) e1 = 0;
                int idx[8];
#pragma unroll
                for (int k = 0; k < 8; ++k) {
                    int p = beg + k; if (p > e1) p = e1;
                    idx[k] = elist[p];
                }
#pragma unroll
                for (int k = 0; k < 8; ++k)
                    v[t][k] = *(const bf16x2*)(hb + (size_t)idx[k] * DD);
            }
#pragma unroll
            for (int t = 0; t < 4; ++t) {
#pragma unroll
                for (int k = 0; k < 8; ++k) {
                    float m = (nb[t] > k) ? 1.f : 0.f;
                    ax[t] += m * (float)v[t][k].x;
                    ay[t] += m * (float)v[t][k].y;
                }
            }
            // tails (deg > 8 per type, rare)
#pragma unroll
            for (int t = 0; t < 4; ++t) {
                int end = ends[t];
                for (int base = begs[t] + 8; base < end; base += 8) {
                    int nb2 = end - base; if (nb2 > 8) nb2 = 8;
                    int e1 = end - 1;
                    int idx[8];
#pragma unroll
                    for (int k = 0; k < 8; ++k) {
                        int p = base + k; if (p > e1) p = e1;
                        idx[k] = elist[p];
                    }
                    bf16x2 tv[8];
#pragma unroll
                    for (int k = 0; k < 8; ++k)
                        tv[k] = *(const bf16x2*)(hb + (size_t)idx[k] * DD);
#pragma unroll
                    for (int k = 0; k < 8; ++k) {
                        float m = (nb2 > k) ? 1.f : 0.f;
                        ax[t] += m * (float)tv[k].x;
                        ay[t] += m * (float)tv[k].y;
                    }
                }
            }
#pragma unroll
            for (int t = 0; t < 4; ++t) {
                bf16x2 o;
                o.x = (__bf16)ax[t];
                o.y = (__bf16)ay[t];
                *(bf16x2*)(X + (size_t)(ob + t) * 128 + lane * 2) = o;
            }
        }
    }
    __syncthreads();   // X slice complete (covers last-block clamped cross-wave reads)

    bf16x8 a[12];   // phase-B A-fragments: [0..7]=msgs, [8..11]=h

    // ---------------- phase A: M = relu(X @ WK + deg-bias), swapped operands ----------------
    {
        const __bf16* Ap = X + (size_t)arow * 512 + lq * 8;
#pragma unroll
        for (int i = 0; i < 2; ++i) {
            int q = i * 8 + wave;
            GLDS(WK + (size_t)q * 512 + lane * 8, &Bs[0][q * 512]);
        }
        bf16x8 acur = *(const bf16x8*)(Ap);
        f32x4 acc[16] = {};
        __syncthreads();    // stage 0 landed

#pragma unroll 1
        for (int c = 0; c < 16; ++c) {
            int cur = c & 1;
            bf16x8 anext = acur;
            if (c < 15) {
                const __bf16* src = WK + (size_t)(c + 1) * 8192;
#pragma unroll
                for (int i = 0; i < 2; ++i) {
                    int q = i * 8 + wave;
                    GLDS(src + (size_t)q * 512 + lane * 8, &Bs[cur ^ 1][q * 512]);
                }
                anext = *(const bf16x8*)(Ap + (c + 1) * 32);
            }
#pragma unroll
            for (int nt = 0; nt < 16; ++nt) {
                bf16x8 b = *(const bf16x8*)&Bs[cur][((size_t)lq * 256 + nt * 16 + lm) * 8];
                // SWAPPED: A = WK frag, B = X frag  ->  acc[nt] = M^T tile
                acc[nt] = __builtin_amdgcn_mfma_f32_16x16x32_bf16(b, acur, acc[nt], 0, 0, 0);
            }
            __syncthreads();
            acur = anext;
        }
        // epilogue A (registers only): nt-major, float4 bias loads
        int ob2 = arow * TT;
        int q0 = offsets[ob2], q1 = offsets[ob2 + 1], q2 = offsets[ob2 + 2],
            q3 = offsets[ob2 + 3], q4 = offsets[ob2 + 4];
        float n0 = (float)(q1 - q0), n1 = (float)(q2 - q1),
              n2 = (float)(q3 - q2), n3 = (float)(q4 - q3);
#pragma unroll
        for (int nt = 0; nt < 16; ++nt) {
            const float* bp = b_msg + nt * 16 + lq * 4;
            f32x4 b0 = *(const f32x4*)(bp);
            f32x4 b1 = *(const f32x4*)(bp + MM);
            f32x4 b2 = *(const f32x4*)(bp + 2 * MM);
            f32x4 b3 = *(const f32x4*)(bp + 3 * MM);
#pragma unroll
            for (int ii = 0; ii < 4; ++ii) {
                float bias = n0 * b0[ii] + n1 * b1[ii] + n2 * b2[ii] + n3 * b3[ii];
                a[nt >> 1][(nt & 1) * 4 + ii] = (__bf16)fmaxf(acc[nt][ii] + bias, 0.f);
            }
        }
    }

    // ---------------- phase B: GRU ----------------
    // stage (j=0, half=0) -> Bs[0] (Bs dead after phase A's final barrier)
#pragma unroll
    for (int i = 0; i < 3; ++i) {
        int q = i * 8 + wave;
        GLDS(WBj + (size_t)q * 512 + lane * 8, &Bs[0][q * 512]);
    }
    {
        const __bf16* hp = hbc + (size_t)arow * DD + lq * 8;
#pragma unroll
        for (int c2 = 0; c2 < 4; ++c2)
            a[8 + c2] = *(const bf16x8*)(hp + c2 * 32);
    }
    __syncthreads();   // (0,0) landed

#pragma unroll 1
    for (int j = 0; j < 8; ++j) {
        const __bf16* srcj = WBj + (size_t)j * 24576;
        int d = j * 16 + lm;
        int rb = r0 + lq * 4;
        f32x4 ar = {}, az = {}, an = {}, ah = {};

        // ---- phase 2j: stage (j,1)->buf1, prefetch hold, compute half0 from buf0 ----
#pragma unroll
        for (int i = 0; i < 3; ++i) {
            int q = i * 8 + wave;
            GLDS(srcj + 12288 + (size_t)q * 512 + lane * 8, &Bs[1][q * 512]);
        }
        float h0 = hf[(size_t)(rb + 0 < NN ? rb + 0 : NN - 1) * DD + d];
        float h1 = hf[(size_t)(rb + 1 < NN ? rb + 1 : NN - 1) * DD + d];
        float h2 = hf[(size_t)(rb + 2 < NN ? rb + 2 : NN - 1) * DD + d];
        float h3 = hf[(size_t)(rb + 3 < NN ? rb + 3 : NN - 1) * DD + d];
#pragma unroll
        for (int cc = 0; cc < 6; ++cc) {
            const __bf16* Bp = &Bs[0][(cc * 4 + lq) * 512 + lm * 8];
            bf16x8 br = *(const bf16x8*)(Bp);
            bf16x8 bz = *(const bf16x8*)(Bp + 128);
            bf16x8 bn = *(const bf16x8*)(Bp + 256);
            bf16x8 bh = *(const bf16x8*)(Bp + 384);
            ar = __builtin_amdgcn_mfma_f32_16x16x32_bf16(a[cc], br, ar, 0, 0, 0);
            az = __builtin_amdgcn_mfma_f32_16x16x32_bf16(a[cc], bz, az, 0, 0, 0);
            an = __builtin_amdgcn_mfma_f32_16x16x32_bf16(a[cc], bn, an, 0, 0, 0);
            ah = __builtin_amdgcn_mfma_f32_16x16x32_bf16(a[cc], bh, ah, 0, 0, 0);
        }
        __syncthreads();   // (j,1) landed; all waves done with buf0

        // ---- phase 2j+1: stage (j+1,0)->buf0 (if any), compute half1 from buf1 ----
        if (j < 7) {
#pragma unroll
            for (int i = 0; i < 3; ++i) {
                int q = i * 8 + wave;
                GLDS(srcj + 24576 + (size_t)q * 512 + lane * 8, &Bs[0][q * 512]);
            }
        }
#pragma unroll
        for (int cc = 0; cc < 6; ++cc) {
            const __bf16* Bp = &Bs[1][(cc * 4 + lq) * 512 + lm * 8];
            bf16x8 br = *(const bf16x8*)(Bp);
            bf16x8 bz = *(const bf16x8*)(Bp + 128);
            bf16x8 bn = *(const bf16x8*)(Bp + 256);
            bf16x8 bh = *(const bf16x8*)(Bp + 384);
            ar = __builtin_amdgcn_mfma_f32_16x16x32_bf16(a[6 + cc], br, ar, 0, 0, 0);
            az = __builtin_amdgcn_mfma_f32_16x16x32_bf16(a[6 + cc], bz, az, 0, 0, 0);
            an = __builtin_amdgcn_mfma_f32_16x16x32_bf16(a[6 + cc], bn, an, 0, 0, 0);
            ah = __builtin_amdgcn_mfma_f32_16x16x32_bf16(a[6 + cc], bh, ah, 0, 0, 0);
        }
        // ---- epilogue for j (registers + global only) ----
        float cbr = b512[d], cbz = b512[128 + d], cbn = b512[256 + d], cbh = b512[384 + d];
        float hv[4] = {h0, h1, h2, h3};
#pragma unroll
        for (int i = 0; i < 4; ++i) {
            int row = rb + i;
            if (row >= NN) continue;
            float pr  = ar[i] + cbr;
            float pz  = az[i] + cbz;
            float pin = an[i] + cbn;
            float phn = ah[i] + cbh;
            float r = fast_sigmoid(pr);
            float z = fast_sigmoid(pz);
            float nv = fast_tanh(pin + r * phn);
            float hnew = (1.f - z) * nv + z * hv[i];
            hf[(size_t)row * DD + d] = hnew;
            hbc[(size_t)row * DD + d] = (__bf16)hnew;
        }
        __syncthreads();   // (j+1,0) landed; all waves done with buf1
    }
}

// ================= readout =================
__global__ void attn_kernel(const float* __restrict__ hf, const float* __restrict__ w_gate,
                            const float* __restrict__ b_gate, float* __restrict__ attn) {
    int node = blockIdx.x * 4 + (threadIdx.x >> 6);
    int lane = threadIdx.x & 63;
    if (node >= NN) return;
    size_t base = (size_t)node * DD;
    float s = hf[base + lane * 2] * w_gate[lane * 2]
            + hf[base + lane * 2 + 1] * w_gate[lane * 2 + 1];
    for (int off = 32; off; off >>= 1) s += __shfl_down(s, off);
    if (lane == 0) attn[node] = 1.f / (1.f + expf(-(s + b_gate[0])));
}

__global__ void segsum_kernel(const int* __restrict__ goff, const float* __restrict__ attn,
                              const float* __restrict__ hf, float* __restrict__ sg,
                              float* __restrict__ asumg) {
    int g = blockIdx.x;
    int d = threadIdx.x;
    int beg = goff[g], end = goff[g + 1];
    float s = 0.f, asum = 0.f;
    for (int i = beg; i < end; ++i) {
        float a = attn[i];
        s += a * hf[(size_t)i * DD + d];
        if (d == 0) asum += a;
    }
    sg[g * DD + d] = s;
    if (d == 0) asumg[g] = asum;
}

__global__ void readout_kernel(const float* __restrict__ sg, const float* __restrict__ asumg,
                               const float* __restrict__ W_g, const float* __restrict__ b_g,
                               float* __restrict__ hgraph) {
    int g = blockIdx.x;
    int m = threadIdx.x;
    float acc = asumg[g] * b_g[m];
    for (int d = 0; d < DD; ++d) acc += sg[g * DD + d] * W_g[d * GHID + m];
    hgraph[g * GHID + m] = acc;
}

// ================= launch =================
extern "C" void kernel_launch(void* const* d_in, const int* in_sizes, int n_in,
                              void* d_out, int out_size, void* d_ws, size_t ws_size,
                              hipStream_t stream) {
    const int*   node_types = (const int*)d_in[0];
    const int*   edge_src   = (const int*)d_in[1];
    const int*   edge_dst   = (const int*)d_in[2];
    const int*   edge_type  = (const int*)d_in[3];
    const int*   node2graph = (const int*)d_in[4];
    const float* emb        = (const float*)d_in[5];
    const float* W_msg      = (const float*)d_in[6];
    const float* b_msg      = (const float*)d_in[7];
    const float* W_ih       = (const float*)d_in[8];
    const float* W_hh       = (const float*)d_in[9];
    const float* b_ih       = (const float*)d_in[10];
    const float* b_hh       = (const float*)d_in[11];
    const float* w_gate     = (const float*)d_in[12];
    const float* b_gate     = (const float*)d_in[13];
    const float* W_g        = (const float*)d_in[14];
    const float* b_g        = (const float*)d_in[15];

    float* hf     = (float*)d_out;
    float* hgraph = hf + (size_t)NN * DD;

    char* ws = (char*)d_ws;
    size_t off = 0;
    auto alloc = [&](size_t bytes) -> char* {
        char* p = ws + off;
        off += (bytes + 255) & ~(size_t)255;
        return p;
    };
    __bf16* X       = (__bf16*)alloc((size_t)NN * 512 * 2);   // 51.2 MB (block-transient)
    __bf16* hbc     = (__bf16*)alloc((size_t)NN * DD * 2);    // 12.8 MB compact h
    __bf16* WK      = (__bf16*)alloc((size_t)16 * 4 * 256 * 8 * 2);
    __bf16* WB      = (__bf16*)alloc((size_t)12 * 4 * 512 * 8 * 2);
    float*  b512    = (float*)alloc(512 * 4);
    float*  attn    = (float*)alloc((size_t)NN * 4);
    float*  sg      = (float*)alloc((size_t)NG * DD * 4);
    float*  asumg   = (float*)alloc((size_t)NG * 4);
    int*    counts  = (int*)alloc((size_t)(NKEY + 1) * 4);
    int*    offsets = (int*)alloc((size_t)(NKEY + 1) * 4);
    int*    cursor  = (int*)alloc((size_t)(NKEY + 1) * 4);
    int*    bsum    = (int*)alloc((size_t)1024 * 4);
    int*    elist   = (int*)alloc((size_t)NE * 4);
    int*    gcounts = (int*)alloc((size_t)(NG + 1) * 4);
    int*    goff    = (int*)alloc((size_t)(NG + 1) * 4);
    int*    gbsum   = (int*)alloc((size_t)8 * 4);

    hipMemsetAsync(counts, 0, (NKEY + 1) * 4, stream);
    hipMemsetAsync(gcounts, 0, (NG + 1) * 4, stream);

    build_WK<<<(16 * 4 * 256 * 8 + 255) / 256, 256, 0, stream>>>(W_msg, WK);
    build_WBj<<<(12 * 4 * 512 * 8 + 255) / 256, 256, 0, stream>>>(W_ih, W_hh, WB);
    build_bias512<<<2, 256, 0, stream>>>(b_ih, b_hh, b512);
    embed_kernel<<<(NN * DD + 255) / 256, 256, 0, stream>>>(node_types, emb, hf, hbc);

    int nbE = (NKEY + 255) / 256;
    hist_kernel<<<(NE + 255) / 256, 256, 0, stream>>>(edge_src, edge_type, counts);
    scan1<<<nbE, 256, 0, stream>>>(counts, offsets, bsum, NKEY);
    scan2<<<1, 1024, 0, stream>>>(bsum, nbE, offsets, NKEY);
    scan3<<<nbE, 256, 0, stream>>>(offsets, bsum, cursor, NKEY);
    fill_kernel<<<(NE + 255) / 256, 256, 0, stream>>>(edge_src, edge_dst, edge_type, cursor, elist);

    int nbG = (NG + 255) / 256;
    ghist_kernel<<<(NN + 255) / 256, 256, 0, stream>>>(node2graph, gcounts);
    scan1<<<nbG, 256, 0, stream>>>(gcounts, goff, gbsum, NG);
    scan2<<<1, 1024, 0, stream>>>(gbsum, nbG, goff, NG);
    scan3<<<nbG, 256, 0, stream>>>(goff, gbsum, (int*)nullptr, NG);

    int rt2 = (NN + 127) / 128;  // 391
    for (int p = 0; p < NPASS; ++p) {
        msgs_gru<<<rt2, 512, 0, stream>>>(offsets, elist, X, WK, b_msg, WB, b512, hf, hbc);
    }

    attn_kernel<<<(NN + 3) / 4, 256, 0, stream>>>(hf, w_gate, b_gate, attn);
    segsum_kernel<<<NG, 128, 0, stream>>>(goff, attn, hf, sg, asumg);
    readout_kernel<<<NG, GHID, 0, stream>>>(sg, asumg, W_g, b_g, hgraph);
}

// Round 14
// 707.515 us; speedup vs baseline: 1.1684x; 1.1684x over previous
//
#include <hip/hip_runtime.h>
#include <hip/hip_bf16.h>

#define NN 50000
#define NE 800000
#define NG 512
#define DD 128
#define MM 256
#define TT 4
#define NPASS 4
#define GHID 256
#define NKEY (NN * TT)          // CSR keys: src*4 + type

typedef __bf16 bf16x2 __attribute__((ext_vector_type(2)));
typedef __bf16 bf16x4 __attribute__((ext_vector_type(4)));
typedef __bf16 bf16x8 __attribute__((ext_vector_type(8)));
typedef float f32x4 __attribute__((ext_vector_type(4)));

__device__ __forceinline__ float fast_sigmoid(float x) {
    return __builtin_amdgcn_rcpf(1.f + __expf(-x));
}
__device__ __forceinline__ float fast_tanh(float x) {
    float e2 = __expf(2.f * x);
    return 1.f - 2.f * __builtin_amdgcn_rcpf(e2 + 1.f);
}

#define GLDS(SRC, DST) \
    __builtin_amdgcn_global_load_lds( \
        (const __attribute__((address_space(1))) unsigned int*)(SRC), \
        (__attribute__((address_space(3))) unsigned int*)(DST), 16, 0, 0)

// ================= setup: all weight/bias prep in ONE dispatch =================
// grid 768 x 256 = 196608 threads.
//  i < 131072            -> WK[i]
//  i < 196608            -> WB[i]  (j-major GRU layout with pi K-permutation)
//  i < 512               -> b512[i]
__global__ void build_all(const float* __restrict__ W_msg,
                          const float* __restrict__ W_ih, const float* __restrict__ W_hh,
                          const float* __restrict__ b_ih, const float* __restrict__ b_hh,
                          __bf16* __restrict__ WK, __bf16* __restrict__ WB,
                          float* __restrict__ b512) {
    int i = blockIdx.x * 256 + threadIdx.x;
    if (i < 16 * 4 * 256 * 8) {
        int j = i & 7, col = (i >> 3) & 255, g = i >> 11; // g=c*4+lq
        int k = g * 8 + j;
        WK[i] = (__bf16)W_msg[k * 256 + col];
    }
    {
        int low = i & 127;
        int lm = low >> 3, e = low & 7;
        int rest = i >> 7;
        int g  = rest & 3;
        int lq = (rest >> 2) & 3;
        int jc = rest >> 4;          // j*12 + c
        int c  = jc % 12;
        int j  = jc / 12;
        int k   = (c * 4 + lq) * 8 + e;     // 0..383
        int col = g * 128 + j * 16 + lm;    // 0..511
        int korig = k;
        if (k < 256) {                      // pi_inv: k=(c2,lq2,e2) -> col=nt*16+lq2*4+i2
            int c2 = k >> 5, lq2 = (k >> 3) & 3, e2 = k & 7;
            int nt = c2 * 2 + (e2 >> 2), i2 = e2 & 3;
            korig = nt * 16 + lq2 * 4 + i2;
        }
        float v = 0.f;
        if (col < 256) {
            v = (k < 256) ? W_ih[col * 256 + korig] : W_hh[col * 128 + (k - 256)];
        } else if (col < 384) {
            if (k < 256) v = W_ih[col * 256 + korig];
        } else {
            if (k >= 256) v = W_hh[(col - 128) * 128 + (k - 256)];
        }
        WB[i] = (__bf16)v;
    }
    if (i < 512) {
        float v;
        if (i < 256) v = b_ih[i] + b_hh[i];
        else if (i < 384) v = b_ih[i];
        else v = b_hh[i - 128];
        b512[i] = v;
    }
}

// ================= embedding =================
__global__ void embed_kernel(const int* __restrict__ node_types,
                             const float* __restrict__ emb,
                             float* __restrict__ hf, __bf16* __restrict__ hbc) {
    int t = blockIdx.x * 256 + threadIdx.x;
    if (t >= NN * DD) return;
    int node = t >> 7;
    float v = emb[node_types[node] * DD + (t & 127)];
    hf[t] = v;
    hbc[t] = (__bf16)v;
}

// ================= CSR build (keyed by src*4+type) =================
__global__ void hist_kernel(const int* __restrict__ src, const int* __restrict__ et,
                            int* __restrict__ counts) {
    int e = blockIdx.x * 256 + threadIdx.x;
    if (e < NE) atomicAdd(&counts[src[e] * TT + et[e]], 1);
}

__global__ void ghist_kernel(const int* __restrict__ n2g, int* __restrict__ gcounts) {
    int i = blockIdx.x * 256 + threadIdx.x;
    if (i < NN) atomicAdd(&gcounts[n2g[i]], 1);
}

__global__ void scan1(const int* __restrict__ counts, int* __restrict__ offsets,
                      int* __restrict__ bsum, int n) {
    __shared__ int sm[256];
    int i = blockIdx.x * 256 + threadIdx.x;
    int v = (i < n) ? counts[i] : 0;
    sm[threadIdx.x] = v;
    __syncthreads();
    for (int off = 1; off < 256; off <<= 1) {
        int t = (threadIdx.x >= off) ? sm[threadIdx.x - off] : 0;
        __syncthreads();
        sm[threadIdx.x] += t;
        __syncthreads();
    }
    if (i < n) offsets[i] = sm[threadIdx.x] - v;
    if (threadIdx.x == 255) bsum[blockIdx.x] = sm[255];
}

__global__ void scan2(int* __restrict__ bsum, int nb, int* __restrict__ offsets, int n) {
    __shared__ int sm[1024];
    int v = (threadIdx.x < nb) ? bsum[threadIdx.x] : 0;
    sm[threadIdx.x] = v;
    __syncthreads();
    for (int off = 1; off < 1024; off <<= 1) {
        int t = (threadIdx.x >= off) ? sm[threadIdx.x - off] : 0;
        __syncthreads();
        sm[threadIdx.x] += t;
        __syncthreads();
    }
    if (threadIdx.x < nb) bsum[threadIdx.x] = sm[threadIdx.x] - v;
    if (threadIdx.x == 1023) offsets[n] = sm[1023];
}

__global__ void scan3(int* __restrict__ offsets, const int* __restrict__ bsum,
                      int* __restrict__ cursor, int n) {
    int i = blockIdx.x * 256 + threadIdx.x;
    if (i < n) {
        int o = offsets[i] + bsum[blockIdx.x];
        offsets[i] = o;
        if (cursor) cursor[i] = o;
    }
}

// single-block exclusive scan for the 512 graph counts
__global__ void gscan(const int* __restrict__ gcounts, int* __restrict__ goff) {
    __shared__ int sm[512];
    int t = threadIdx.x;
    int v = gcounts[t];
    sm[t] = v;
    __syncthreads();
    for (int off = 1; off < 512; off <<= 1) {
        int x = (t >= off) ? sm[t - off] : 0;
        __syncthreads();
        sm[t] += x;
        __syncthreads();
    }
    goff[t] = sm[t] - v;
    if (t == 511) goff[512] = sm[511];
}

__global__ void fill_kernel(const int* __restrict__ src, const int* __restrict__ dst,
                            const int* __restrict__ et, int* __restrict__ cursor,
                            int* __restrict__ elist) {
    int e = blockIdx.x * 256 + threadIdx.x;
    if (e >= NE) return;
    int pos = atomicAdd(&cursor[src[e] * TT + et[e]], 1);
    elist[pos] = dst[e];
}

// ================= aggregation: wave per SRC ROW (all 4 types), branchless batch-0 =====
__global__ void agg4(const int* __restrict__ offsets, const int* __restrict__ elist,
                     const __bf16* __restrict__ hbc, __bf16* __restrict__ X) {
    int row = blockIdx.x * 4 + (threadIdx.x >> 6);
    if (row >= NN) return;
    int lane = threadIdx.x & 63;
    const __bf16* hb = hbc + lane * 2;
    int ob = row * TT;
    int o0 = __builtin_amdgcn_readfirstlane(offsets[ob]);
    int o1 = __builtin_amdgcn_readfirstlane(offsets[ob + 1]);
    int o2 = __builtin_amdgcn_readfirstlane(offsets[ob + 2]);
    int o3 = __builtin_amdgcn_readfirstlane(offsets[ob + 3]);
    int o4 = __builtin_amdgcn_readfirstlane(offsets[ob + 4]);
    int begs[4] = {o0, o1, o2, o3};
    int ends[4] = {o1, o2, o3, o4};

    float ax[4] = {0.f, 0.f, 0.f, 0.f};
    float ay[4] = {0.f, 0.f, 0.f, 0.f};

    // ---- batch 0: 8 clamped gathers x 4 types, ALL issued before any accumulate ----
    bf16x2 v[4][8];
    int nb[4];
#pragma unroll
    for (int t = 0; t < 4; ++t) {
        int beg = begs[t], end = ends[t];
        nb[t] = end - beg;
        int e1 = end - 1;
        if (e1 < 0) e1 = 0;
        int idx[8];
#pragma unroll
        for (int k = 0; k < 8; ++k) {
            int p = beg + k; if (p > e1) p = e1;
            idx[k] = elist[p];
        }
#pragma unroll
        for (int k = 0; k < 8; ++k)
            v[t][k] = *(const bf16x2*)(hb + (size_t)idx[k] * DD);
    }
#pragma unroll
    for (int t = 0; t < 4; ++t) {
#pragma unroll
        for (int k = 0; k < 8; ++k) {
            float m = (nb[t] > k) ? 1.f : 0.f;
            ax[t] += m * (float)v[t][k].x;
            ay[t] += m * (float)v[t][k].y;
        }
    }

    // ---- tails (deg > 8 per type, rare) ----
#pragma unroll
    for (int t = 0; t < 4; ++t) {
        int end = ends[t];
        for (int base = begs[t] + 8; base < end; base += 8) {
            int nb2 = end - base; if (nb2 > 8) nb2 = 8;
            int e1 = end - 1;
            int idx[8];
#pragma unroll
            for (int k = 0; k < 8; ++k) {
                int p = base + k; if (p > e1) p = e1;
                idx[k] = elist[p];
            }
            bf16x2 tv[8];
#pragma unroll
            for (int k = 0; k < 8; ++k)
                tv[k] = *(const bf16x2*)(hb + (size_t)idx[k] * DD);
#pragma unroll
            for (int k = 0; k < 8; ++k) {
                float m = (nb2 > k) ? 1.f : 0.f;
                ax[t] += m * (float)tv[k].x;
                ay[t] += m * (float)tv[k].y;
            }
        }
    }

#pragma unroll
    for (int t = 0; t < 4; ++t) {
        bf16x2 o;
        o.x = (__bf16)ax[t];
        o.y = (__bf16)ay[t];
        *(bf16x2*)(X + (size_t)(ob + t) * 128 + lane * 2) = o;
    }
}

// ================= FUSED msgs GEMM + GRU GEMM (register handoff, 8-wave block) ======
__global__ __launch_bounds__(512, 4)
void msgs_gru(const __bf16* __restrict__ X, const __bf16* __restrict__ WK,
              const float* __restrict__ b_msg, const int* __restrict__ offsets,
              const __bf16* __restrict__ WBj, const float* __restrict__ b512,
              float* __restrict__ hf, __bf16* __restrict__ hbc) {
    __shared__ __bf16 Bs[2][12288];   // 48 KB total -> 3 blocks/CU
    int tid = threadIdx.x, wave = tid >> 6, lane = tid & 63;
    int lm = lane & 15, lq = lane >> 4;
    int r0 = blockIdx.x * 128 + wave * 16;
    int arow = r0 + lm; if (arow >= NN) arow = NN - 1;

    bf16x8 a[12];   // phase-B A-fragments: [0..7]=msgs, [8..11]=h

    // ---------------- phase A: M = relu(X @ WK + deg-bias), swapped operands ----------------
    {
        const __bf16* Ap = X + (size_t)arow * 512 + lq * 8;
#pragma unroll
        for (int i = 0; i < 2; ++i) {
            int q = i * 8 + wave;
            GLDS(WK + (size_t)q * 512 + lane * 8, &Bs[0][q * 512]);
        }
        bf16x8 acur = *(const bf16x8*)(Ap);
        f32x4 acc[16] = {};
        __syncthreads();    // stage 0 landed

#pragma unroll 1
        for (int c = 0; c < 16; ++c) {
            int cur = c & 1;
            bf16x8 anext = acur;
            if (c < 15) {
                const __bf16* src = WK + (size_t)(c + 1) * 8192;
#pragma unroll
                for (int i = 0; i < 2; ++i) {
                    int q = i * 8 + wave;
                    GLDS(src + (size_t)q * 512 + lane * 8, &Bs[cur ^ 1][q * 512]);
                }
                anext = *(const bf16x8*)(Ap + (c + 1) * 32);
            }
#pragma unroll
            for (int nt = 0; nt < 16; ++nt) {
                bf16x8 b = *(const bf16x8*)&Bs[cur][((size_t)lq * 256 + nt * 16 + lm) * 8];
                // SWAPPED: A = WK frag, B = X frag  ->  acc[nt] = M^T tile
                acc[nt] = __builtin_amdgcn_mfma_f32_16x16x32_bf16(b, acur, acc[nt], 0, 0, 0);
            }
            __syncthreads();
            acur = anext;
        }
        // epilogue A (registers only): nt-major, float4 bias loads
        int ob2 = arow * TT;
        int q0 = offsets[ob2], q1 = offsets[ob2 + 1], q2 = offsets[ob2 + 2],
            q3 = offsets[ob2 + 3], q4 = offsets[ob2 + 4];
        float n0 = (float)(q1 - q0), n1 = (float)(q2 - q1),
              n2 = (float)(q3 - q2), n3 = (float)(q4 - q3);
#pragma unroll
        for (int nt = 0; nt < 16; ++nt) {
            const float* bp = b_msg + nt * 16 + lq * 4;
            f32x4 b0 = *(const f32x4*)(bp);
            f32x4 b1 = *(const f32x4*)(bp + MM);
            f32x4 b2 = *(const f32x4*)(bp + 2 * MM);
            f32x4 b3 = *(const f32x4*)(bp + 3 * MM);
#pragma unroll
            for (int ii = 0; ii < 4; ++ii) {
                float bias = n0 * b0[ii] + n1 * b1[ii] + n2 * b2[ii] + n3 * b3[ii];
                a[nt >> 1][(nt & 1) * 4 + ii] = (__bf16)fmaxf(acc[nt][ii] + bias, 0.f);
            }
        }
    }

    // ---------------- phase B: GRU ----------------
#pragma unroll
    for (int i = 0; i < 3; ++i) {
        int q = i * 8 + wave;
        GLDS(WBj + (size_t)q * 512 + lane * 8, &Bs[0][q * 512]);
    }
    {
        const __bf16* hp = hbc + (size_t)arow * DD + lq * 8;
#pragma unroll
        for (int c2 = 0; c2 < 4; ++c2)
            a[8 + c2] = *(const bf16x8*)(hp + c2 * 32);
    }
    __syncthreads();   // (0,0) landed

#pragma unroll 1
    for (int j = 0; j < 8; ++j) {
        const __bf16* srcj = WBj + (size_t)j * 24576;
        int d = j * 16 + lm;
        int rb = r0 + lq * 4;
        f32x4 ar = {}, az = {}, an = {}, ah = {};

        // ---- phase 2j: stage (j,1)->buf1, prefetch hold, compute half0 from buf0 ----
#pragma unroll
        for (int i = 0; i < 3; ++i) {
            int q = i * 8 + wave;
            GLDS(srcj + 12288 + (size_t)q * 512 + lane * 8, &Bs[1][q * 512]);
        }
        float h0 = hf[(size_t)(rb + 0 < NN ? rb + 0 : NN - 1) * DD + d];
        float h1 = hf[(size_t)(rb + 1 < NN ? rb + 1 : NN - 1) * DD + d];
        float h2 = hf[(size_t)(rb + 2 < NN ? rb + 2 : NN - 1) * DD + d];
        float h3 = hf[(size_t)(rb + 3 < NN ? rb + 3 : NN - 1) * DD + d];
#pragma unroll
        for (int cc = 0; cc < 6; ++cc) {
            const __bf16* Bp = &Bs[0][(cc * 4 + lq) * 512 + lm * 8];
            bf16x8 br = *(const bf16x8*)(Bp);
            bf16x8 bz = *(const bf16x8*)(Bp + 128);
            bf16x8 bn = *(const bf16x8*)(Bp + 256);
            bf16x8 bh = *(const bf16x8*)(Bp + 384);
            ar = __builtin_amdgcn_mfma_f32_16x16x32_bf16(a[cc], br, ar, 0, 0, 0);
            az = __builtin_amdgcn_mfma_f32_16x16x32_bf16(a[cc], bz, az, 0, 0, 0);
            an = __builtin_amdgcn_mfma_f32_16x16x32_bf16(a[cc], bn, an, 0, 0, 0);
            ah = __builtin_amdgcn_mfma_f32_16x16x32_bf16(a[cc], bh, ah, 0, 0, 0);
        }
        __syncthreads();   // (j,1) landed; all waves done with buf0

        // ---- phase 2j+1: stage (j+1,0)->buf0 (if any), compute half1 from buf1 ----
        if (j < 7) {
#pragma unroll
            for (int i = 0; i < 3; ++i) {
                int q = i * 8 + wave;
                GLDS(srcj + 24576 + (size_t)q * 512 + lane * 8, &Bs[0][q * 512]);
            }
        }
#pragma unroll
        for (int cc = 0; cc < 6; ++cc) {
            const __bf16* Bp = &Bs[1][(cc * 4 + lq) * 512 + lm * 8];
            bf16x8 br = *(const bf16x8*)(Bp);
            bf16x8 bz = *(const bf16x8*)(Bp + 128);
            bf16x8 bn = *(const bf16x8*)(Bp + 256);
            bf16x8 bh = *(const bf16x8*)(Bp + 384);
            ar = __builtin_amdgcn_mfma_f32_16x16x32_bf16(a[6 + cc], br, ar, 0, 0, 0);
            az = __builtin_amdgcn_mfma_f32_16x16x32_bf16(a[6 + cc], bz, az, 0, 0, 0);
            an = __builtin_amdgcn_mfma_f32_16x16x32_bf16(a[6 + cc], bn, an, 0, 0, 0);
            ah = __builtin_amdgcn_mfma_f32_16x16x32_bf16(a[6 + cc], bh, ah, 0, 0, 0);
        }
        // ---- epilogue for j (registers + global only) ----
        float cbr = b512[d], cbz = b512[128 + d], cbn = b512[256 + d], cbh = b512[384 + d];
        float hv[4] = {h0, h1, h2, h3};
#pragma unroll
        for (int i = 0; i < 4; ++i) {
            int row = rb + i;
            if (row >= NN) continue;
            float pr  = ar[i] + cbr;
            float pz  = az[i] + cbz;
            float pin = an[i] + cbn;
            float phn = ah[i] + cbh;
            float r = fast_sigmoid(pr);
            float z = fast_sigmoid(pz);
            float nv = fast_tanh(pin + r * phn);
            float hnew = (1.f - z) * nv + z * hv[i];
            hf[(size_t)row * DD + d] = hnew;
            hbc[(size_t)row * DD + d] = (__bf16)hnew;
        }
        __syncthreads();   // (j+1,0) landed; all waves done with buf1
    }
}

// ================= readout =================
__global__ void attn_kernel(const float* __restrict__ hf, const float* __restrict__ w_gate,
                            const float* __restrict__ b_gate, float* __restrict__ attn) {
    int node = blockIdx.x * 4 + (threadIdx.x >> 6);
    int lane = threadIdx.x & 63;
    if (node >= NN) return;
    size_t base = (size_t)node * DD;
    float s = hf[base + lane * 2] * w_gate[lane * 2]
            + hf[base + lane * 2 + 1] * w_gate[lane * 2 + 1];
    for (int off = 32; off; off >>= 1) s += __shfl_down(s, off);
    if (lane == 0) attn[node] = 1.f / (1.f + expf(-(s + b_gate[0])));
}

__global__ void segsum_kernel(const int* __restrict__ goff, const float* __restrict__ attn,
                              const float* __restrict__ hf, float* __restrict__ sg,
                              float* __restrict__ asumg) {
    int g = blockIdx.x;
    int d = threadIdx.x;
    int beg = goff[g], end = goff[g + 1];
    float s0 = 0.f, s1 = 0.f, s2 = 0.f, s3 = 0.f, asum = 0.f;
    int i = beg;
    for (; i + 3 < end; i += 4) {
        float a0 = attn[i], a1 = attn[i + 1], a2 = attn[i + 2], a3 = attn[i + 3];
        float v0 = hf[(size_t)i * DD + d];
        float v1 = hf[(size_t)(i + 1) * DD + d];
        float v2 = hf[(size_t)(i + 2) * DD + d];
        float v3 = hf[(size_t)(i + 3) * DD + d];
        s0 += a0 * v0; s1 += a1 * v1; s2 += a2 * v2; s3 += a3 * v3;
        if (d == 0) asum += a0 + a1 + a2 + a3;
    }
    for (; i < end; ++i) {
        float a = attn[i];
        s0 += a * hf[(size_t)i * DD + d];
        if (d == 0) asum += a;
    }
    sg[g * DD + d] = s0 + s1 + s2 + s3;
    if (d == 0) asumg[g] = asum;
}

__global__ void readout_kernel(const float* __restrict__ sg, const float* __restrict__ asumg,
                               const float* __restrict__ W_g, const float* __restrict__ b_g,
                               float* __restrict__ hgraph) {
    int g = blockIdx.x;
    int m = threadIdx.x;
    float acc = asumg[g] * b_g[m];
    for (int d = 0; d < DD; ++d) acc += sg[g * DD + d] * W_g[d * GHID + m];
    hgraph[g * GHID + m] = acc;
}

// ================= launch =================
extern "C" void kernel_launch(void* const* d_in, const int* in_sizes, int n_in,
                              void* d_out, int out_size, void* d_ws, size_t ws_size,
                              hipStream_t stream) {
    const int*   node_types = (const int*)d_in[0];
    const int*   edge_src   = (const int*)d_in[1];
    const int*   edge_dst   = (const int*)d_in[2];
    const int*   edge_type  = (const int*)d_in[3];
    const int*   node2graph = (const int*)d_in[4];
    const float* emb        = (const float*)d_in[5];
    const float* W_msg      = (const float*)d_in[6];
    const float* b_msg      = (const float*)d_in[7];
    const float* W_ih       = (const float*)d_in[8];
    const float* W_hh       = (const float*)d_in[9];
    const float* b_ih       = (const float*)d_in[10];
    const float* b_hh       = (const float*)d_in[11];
    const float* w_gate     = (const float*)d_in[12];
    const float* b_gate     = (const float*)d_in[13];
    const float* W_g        = (const float*)d_in[14];
    const float* b_g        = (const float*)d_in[15];

    float* hf     = (float*)d_out;
    float* hgraph = hf + (size_t)NN * DD;

    char* ws = (char*)d_ws;
    size_t off = 0;
    auto alloc = [&](size_t bytes) -> char* {
        char* p = ws + off;
        off += (bytes + 255) & ~(size_t)255;
        return p;
    };
    __bf16* X       = (__bf16*)alloc((size_t)NN * 512 * 2);   // 51.2 MB
    __bf16* hbc     = (__bf16*)alloc((size_t)NN * DD * 2);    // 12.8 MB compact h
    __bf16* WK      = (__bf16*)alloc((size_t)16 * 4 * 256 * 8 * 2);
    __bf16* WB      = (__bf16*)alloc((size_t)12 * 4 * 512 * 8 * 2);
    float*  b512    = (float*)alloc(512 * 4);
    float*  attn    = (float*)alloc((size_t)NN * 4);
    float*  sg      = (float*)alloc((size_t)NG * DD * 4);
    float*  asumg   = (float*)alloc((size_t)NG * 4);
    int*    counts  = (int*)alloc((size_t)(NKEY + 1) * 4);
    int*    offsets = (int*)alloc((size_t)(NKEY + 1) * 4);
    int*    cursor  = (int*)alloc((size_t)(NKEY + 1) * 4);
    int*    bsum    = (int*)alloc((size_t)1024 * 4);
    int*    elist   = (int*)alloc((size_t)NE * 4);
    int*    gcounts = (int*)alloc((size_t)(NG + 1) * 4);
    int*    goff    = (int*)alloc((size_t)(NG + 1) * 4);

    hipMemsetAsync(counts, 0, (NKEY + 1) * 4, stream);
    hipMemsetAsync(gcounts, 0, (NG + 1) * 4, stream);

    build_all<<<768, 256, 0, stream>>>(W_msg, W_ih, W_hh, b_ih, b_hh, WK, WB, b512);
    embed_kernel<<<(NN * DD + 255) / 256, 256, 0, stream>>>(node_types, emb, hf, hbc);

    int nbE = (NKEY + 255) / 256;
    hist_kernel<<<(NE + 255) / 256, 256, 0, stream>>>(edge_src, edge_type, counts);
    scan1<<<nbE, 256, 0, stream>>>(counts, offsets, bsum, NKEY);
    scan2<<<1, 1024, 0, stream>>>(bsum, nbE, offsets, NKEY);
    scan3<<<nbE, 256, 0, stream>>>(offsets, bsum, cursor, NKEY);
    fill_kernel<<<(NE + 255) / 256, 256, 0, stream>>>(edge_src, edge_dst, edge_type, cursor, elist);

    ghist_kernel<<<(NN + 255) / 256, 256, 0, stream>>>(node2graph, gcounts);
    gscan<<<1, 512, 0, stream>>>(gcounts, goff);

    int rt2 = (NN + 127) / 128;  // 391
    for (int p = 0; p < NPASS; ++p) {
        agg4<<<(NN + 3) / 4, 256, 0, stream>>>(offsets, elist, hbc, X);
        msgs_gru<<<rt2, 512, 0, stream>>>(X, WK, b_msg, offsets, WB, b512, hf, hbc);
    }

    attn_kernel<<<(NN + 3) / 4, 256, 0, stream>>>(hf, w_gate, b_gate, attn);
    segsum_kernel<<<NG, 128, 0, stream>>>(goff, attn, hf, sg, asumg);
    readout_kernel<<<NG, GHID, 0, stream>>>(sg, asumg, W_g, b_g, hgraph);
}

// Round 15
// 632.926 us; speedup vs baseline: 1.3061x; 1.1178x over previous
//
#include <hip/hip_runtime.h>
#include <hip/hip_bf16.h>

#define NN 50000
#define NE 800000
#define NG 512
#define DD 128
#define MM 256
#define TT 4
#define NPASS 4
#define GHID 256
#define NKEY (NN * TT)          // CSR keys: src*4 + type

typedef __bf16 bf16x2 __attribute__((ext_vector_type(2)));
typedef __bf16 bf16x4 __attribute__((ext_vector_type(4)));
typedef __bf16 bf16x8 __attribute__((ext_vector_type(8)));
typedef float f32x4 __attribute__((ext_vector_type(4)));

__device__ __forceinline__ float fast_sigmoid(float x) {
    return __builtin_amdgcn_rcpf(1.f + __expf(-x));
}
__device__ __forceinline__ float fast_tanh(float x) {
    float e2 = __expf(2.f * x);
    return 1.f - 2.f * __builtin_amdgcn_rcpf(e2 + 1.f);
}

#define GLDS(SRC, DST) \
    __builtin_amdgcn_global_load_lds( \
        (const __attribute__((address_space(1))) unsigned int*)(SRC), \
        (__attribute__((address_space(3))) unsigned int*)(DST), 16, 0, 0)

// ================= setup: all weight/bias prep in ONE dispatch =================
__global__ void build_all(const float* __restrict__ W_msg,
                          const float* __restrict__ W_ih, const float* __restrict__ W_hh,
                          const float* __restrict__ b_ih, const float* __restrict__ b_hh,
                          __bf16* __restrict__ WK, __bf16* __restrict__ WB,
                          float* __restrict__ b512) {
    int i = blockIdx.x * 256 + threadIdx.x;
    if (i < 16 * 4 * 256 * 8) {
        int j = i & 7, col = (i >> 3) & 255, g = i >> 11; // g=c*4+lq
        int k = g * 8 + j;
        WK[i] = (__bf16)W_msg[k * 256 + col];
    }
    {
        int low = i & 127;
        int lm = low >> 3, e = low & 7;
        int rest = i >> 7;
        int g  = rest & 3;
        int lq = (rest >> 2) & 3;
        int jc = rest >> 4;          // j*12 + c
        int c  = jc % 12;
        int j  = jc / 12;
        int k   = (c * 4 + lq) * 8 + e;     // 0..383
        int col = g * 128 + j * 16 + lm;    // 0..511
        int korig = k;
        if (k < 256) {                      // pi_inv: k=(c2,lq2,e2) -> col=nt*16+lq2*4+i2
            int c2 = k >> 5, lq2 = (k >> 3) & 3, e2 = k & 7;
            int nt = c2 * 2 + (e2 >> 2), i2 = e2 & 3;
            korig = nt * 16 + lq2 * 4 + i2;
        }
        float v = 0.f;
        if (col < 256) {
            v = (k < 256) ? W_ih[col * 256 + korig] : W_hh[col * 128 + (k - 256)];
        } else if (col < 384) {
            if (k < 256) v = W_ih[col * 256 + korig];
        } else {
            if (k >= 256) v = W_hh[(col - 128) * 128 + (k - 256)];
        }
        WB[i] = (__bf16)v;
    }
    if (i < 512) {
        float v;
        if (i < 256) v = b_ih[i] + b_hh[i];
        else if (i < 384) v = b_ih[i];
        else v = b_hh[i - 128];
        b512[i] = v;
    }
}

// ================= embedding =================
__global__ void embed_kernel(const int* __restrict__ node_types,
                             const float* __restrict__ emb,
                             float* __restrict__ hf, __bf16* __restrict__ hbc) {
    int t = blockIdx.x * 256 + threadIdx.x;
    if (t >= NN * DD) return;
    int node = t >> 7;
    float v = emb[node_types[node] * DD + (t & 127)];
    hf[t] = v;
    hbc[t] = (__bf16)v;
}

// ================= CSR build (keyed by src*4+type) =================
__global__ void hist_kernel(const int* __restrict__ src, const int* __restrict__ et,
                            int* __restrict__ counts) {
    int e = blockIdx.x * 256 + threadIdx.x;
    if (e < NE) atomicAdd(&counts[src[e] * TT + et[e]], 1);
}

__global__ void ghist_kernel(const int* __restrict__ n2g, int* __restrict__ gcounts) {
    int i = blockIdx.x * 256 + threadIdx.x;
    if (i < NN) atomicAdd(&gcounts[n2g[i]], 1);
}

__global__ void scan1(const int* __restrict__ counts, int* __restrict__ offsets,
                      int* __restrict__ bsum, int n) {
    __shared__ int sm[256];
    int i = blockIdx.x * 256 + threadIdx.x;
    int v = (i < n) ? counts[i] : 0;
    sm[threadIdx.x] = v;
    __syncthreads();
    for (int off = 1; off < 256; off <<= 1) {
        int t = (threadIdx.x >= off) ? sm[threadIdx.x - off] : 0;
        __syncthreads();
        sm[threadIdx.x] += t;
        __syncthreads();
    }
    if (i < n) offsets[i] = sm[threadIdx.x] - v;
    if (threadIdx.x == 255) bsum[blockIdx.x] = sm[255];
}

__global__ void scan2(int* __restrict__ bsum, int nb, int* __restrict__ offsets, int n) {
    __shared__ int sm[1024];
    int v = (threadIdx.x < nb) ? bsum[threadIdx.x] : 0;
    sm[threadIdx.x] = v;
    __syncthreads();
    for (int off = 1; off < 1024; off <<= 1) {
        int t = (threadIdx.x >= off) ? sm[threadIdx.x - off] : 0;
        __syncthreads();
        sm[threadIdx.x] += t;
        __syncthreads();
    }
    if (threadIdx.x < nb) bsum[threadIdx.x] = sm[threadIdx.x] - v;
    if (threadIdx.x == 1023) offsets[n] = sm[1023];
}

__global__ void scan3(int* __restrict__ offsets, const int* __restrict__ bsum,
                      int* __restrict__ cursor, int n) {
    int i = blockIdx.x * 256 + threadIdx.x;
    if (i < n) {
        int o = offsets[i] + bsum[blockIdx.x];
        offsets[i] = o;
        if (cursor) cursor[i] = o;
    }
}

// single-block exclusive scan for the 512 graph counts
__global__ void gscan(const int* __restrict__ gcounts, int* __restrict__ goff) {
    __shared__ int sm[512];
    int t = threadIdx.x;
    int v = gcounts[t];
    sm[t] = v;
    __syncthreads();
    for (int off = 1; off < 512; off <<= 1) {
        int x = (t >= off) ? sm[t - off] : 0;
        __syncthreads();
        sm[t] += x;
        __syncthreads();
    }
    goff[t] = sm[t] - v;
    if (t == 511) goff[512] = sm[511];
}

__global__ void fill_kernel(const int* __restrict__ src, const int* __restrict__ dst,
                            const int* __restrict__ et, int* __restrict__ cursor,
                            int* __restrict__ elist) {
    int e = blockIdx.x * 256 + threadIdx.x;
    if (e >= NE) return;
    int pos = atomicAdd(&cursor[src[e] * TT + et[e]], 1);
    elist[pos] = dst[e];
}

// ================= aggregation: wave per SRC ROW (all 4 types), branchless batch-0 =====
__global__ void agg4(const int* __restrict__ offsets, const int* __restrict__ elist,
                     const __bf16* __restrict__ hbc, __bf16* __restrict__ X) {
    int row = blockIdx.x * 4 + (threadIdx.x >> 6);
    if (row >= NN) return;
    int lane = threadIdx.x & 63;
    const __bf16* hb = hbc + lane * 2;
    int ob = row * TT;
    int o0 = __builtin_amdgcn_readfirstlane(offsets[ob]);
    int o1 = __builtin_amdgcn_readfirstlane(offsets[ob + 1]);
    int o2 = __builtin_amdgcn_readfirstlane(offsets[ob + 2]);
    int o3 = __builtin_amdgcn_readfirstlane(offsets[ob + 3]);
    int o4 = __builtin_amdgcn_readfirstlane(offsets[ob + 4]);
    int begs[4] = {o0, o1, o2, o3};
    int ends[4] = {o1, o2, o3, o4};

    float ax[4] = {0.f, 0.f, 0.f, 0.f};
    float ay[4] = {0.f, 0.f, 0.f, 0.f};

    // ---- batch 0: 8 clamped gathers x 4 types, ALL issued before any accumulate ----
    bf16x2 v[4][8];
    int nb[4];
#pragma unroll
    for (int t = 0; t < 4; ++t) {
        int beg = begs[t], end = ends[t];
        nb[t] = end - beg;
        int e1 = end - 1;
        if (e1 < 0) e1 = 0;
        int idx[8];
#pragma unroll
        for (int k = 0; k < 8; ++k) {
            int p = beg + k; if (p > e1) p = e1;
            idx[k] = elist[p];
        }
#pragma unroll
        for (int k = 0; k < 8; ++k)
            v[t][k] = *(const bf16x2*)(hb + (size_t)idx[k] * DD);
    }
#pragma unroll
    for (int t = 0; t < 4; ++t) {
#pragma unroll
        for (int k = 0; k < 8; ++k) {
            float m = (nb[t] > k) ? 1.f : 0.f;
            ax[t] += m * (float)v[t][k].x;
            ay[t] += m * (float)v[t][k].y;
        }
    }

    // ---- tails (deg > 8 per type, rare) ----
#pragma unroll
    for (int t = 0; t < 4; ++t) {
        int end = ends[t];
        for (int base = begs[t] + 8; base < end; base += 8) {
            int nb2 = end - base; if (nb2 > 8) nb2 = 8;
            int e1 = end - 1;
            int idx[8];
#pragma unroll
            for (int k = 0; k < 8; ++k) {
                int p = base + k; if (p > e1) p = e1;
                idx[k] = elist[p];
            }
            bf16x2 tv[8];
#pragma unroll
            for (int k = 0; k < 8; ++k)
                tv[k] = *(const bf16x2*)(hb + (size_t)idx[k] * DD);
#pragma unroll
            for (int k = 0; k < 8; ++k) {
                float m = (nb2 > k) ? 1.f : 0.f;
                ax[t] += m * (float)tv[k].x;
                ay[t] += m * (float)tv[k].y;
            }
        }
    }

#pragma unroll
    for (int t = 0; t < 4; ++t) {
        bf16x2 o;
        o.x = (__bf16)ax[t];
        o.y = (__bf16)ay[t];
        *(bf16x2*)(X + (size_t)(ob + t) * 128 + lane * 2) = o;
    }
}

// ================= FUSED msgs GEMM + GRU GEMM (register handoff, 8-wave block) ======
// byte-exact restore of the R12 (669 us) version.
__global__ __launch_bounds__(512, 4)
void msgs_gru(const __bf16* __restrict__ X, const __bf16* __restrict__ WK,
              const float* __restrict__ b_msg, const int* __restrict__ offsets,
              const __bf16* __restrict__ WBj, const float* __restrict__ b512,
              float* __restrict__ hf, __bf16* __restrict__ hbc) {
    __shared__ __bf16 Bs[2][12288];   // 48 KB total
    int tid = threadIdx.x, wave = tid >> 6, lane = tid & 63;
    int lm = lane & 15, lq = lane >> 4;
    int r0 = blockIdx.x * 128 + wave * 16;
    int arow = r0 + lm; if (arow >= NN) arow = NN - 1;

    bf16x8 a[12];   // phase-B A-fragments: [0..7]=msgs, [8..11]=h

    // ---------------- phase A: M = relu(X @ WK + deg-bias), swapped operands ----------------
    {
        const __bf16* Ap = X + (size_t)arow * 512 + lq * 8;
#pragma unroll
        for (int i = 0; i < 2; ++i) {
            int q = i * 8 + wave;
            GLDS(WK + (size_t)q * 512 + lane * 8, &Bs[0][q * 512]);
        }
        bf16x8 acur = *(const bf16x8*)(Ap);
        f32x4 acc[16] = {};
        __syncthreads();    // stage 0 landed

#pragma unroll 1
        for (int c = 0; c < 16; ++c) {
            int cur = c & 1;
            bf16x8 anext = acur;
            if (c < 15) {
                const __bf16* src = WK + (size_t)(c + 1) * 8192;
#pragma unroll
                for (int i = 0; i < 2; ++i) {
                    int q = i * 8 + wave;
                    GLDS(src + (size_t)q * 512 + lane * 8, &Bs[cur ^ 1][q * 512]);
                }
                anext = *(const bf16x8*)(Ap + (c + 1) * 32);
            }
#pragma unroll
            for (int nt = 0; nt < 16; ++nt) {
                bf16x8 b = *(const bf16x8*)&Bs[cur][((size_t)lq * 256 + nt * 16 + lm) * 8];
                // SWAPPED: A = WK frag, B = X frag  ->  acc[nt] = M^T tile
                acc[nt] = __builtin_amdgcn_mfma_f32_16x16x32_bf16(b, acur, acc[nt], 0, 0, 0);
            }
            __syncthreads();
            acur = anext;
        }
        // epilogue A (registers only): bias by row-lm degrees, relu, pack to bf16x8
        int ob2 = arow * TT;
        int q0 = offsets[ob2], q1 = offsets[ob2 + 1], q2 = offsets[ob2 + 2],
            q3 = offsets[ob2 + 3], q4 = offsets[ob2 + 4];
        float n0 = (float)(q1 - q0), n1 = (float)(q2 - q1),
              n2 = (float)(q3 - q2), n3 = (float)(q4 - q3);
#pragma unroll
        for (int c = 0; c < 8; ++c) {
#pragma unroll
            for (int e = 0; e < 8; ++e) {
                int nt = c * 2 + (e >> 2), ii = e & 3;
                int col = nt * 16 + lq * 4 + ii;
                float bias = n0 * b_msg[col] + n1 * b_msg[MM + col]
                           + n2 * b_msg[2 * MM + col] + n3 * b_msg[3 * MM + col];
                a[c][e] = (__bf16)fmaxf(acc[nt][ii] + bias, 0.f);
            }
        }
    }

    // ---------------- phase B: GRU ----------------
#pragma unroll
    for (int i = 0; i < 3; ++i) {
        int q = i * 8 + wave;
        GLDS(WBj + (size_t)q * 512 + lane * 8, &Bs[0][q * 512]);
    }
    {
        const __bf16* hp = hbc + (size_t)arow * DD + lq * 8;
#pragma unroll
        for (int c2 = 0; c2 < 4; ++c2)
            a[8 + c2] = *(const bf16x8*)(hp + c2 * 32);
    }
    __syncthreads();   // (0,0) landed

#pragma unroll 1
    for (int j = 0; j < 8; ++j) {
        const __bf16* srcj = WBj + (size_t)j * 24576;
        int d = j * 16 + lm;
        int rb = r0 + lq * 4;
        f32x4 ar = {}, az = {}, an = {}, ah = {};

        // ---- phase 2j: stage (j,1)->buf1, prefetch hold, compute half0 from buf0 ----
#pragma unroll
        for (int i = 0; i < 3; ++i) {
            int q = i * 8 + wave;
            GLDS(srcj + 12288 + (size_t)q * 512 + lane * 8, &Bs[1][q * 512]);
        }
        float h0 = hf[(size_t)(rb + 0 < NN ? rb + 0 : NN - 1) * DD + d];
        float h1 = hf[(size_t)(rb + 1 < NN ? rb + 1 : NN - 1) * DD + d];
        float h2 = hf[(size_t)(rb + 2 < NN ? rb + 2 : NN - 1) * DD + d];
        float h3 = hf[(size_t)(rb + 3 < NN ? rb + 3 : NN - 1) * DD + d];
#pragma unroll
        for (int cc = 0; cc < 6; ++cc) {
            const __bf16* Bp = &Bs[0][(cc * 4 + lq) * 512 + lm * 8];
            bf16x8 br = *(const bf16x8*)(Bp);
            bf16x8 bz = *(const bf16x8*)(Bp + 128);
            bf16x8 bn = *(const bf16x8*)(Bp + 256);
            bf16x8 bh = *(const bf16x8*)(Bp + 384);
            ar = __builtin_amdgcn_mfma_f32_16x16x32_bf16(a[cc], br, ar, 0, 0, 0);
            az = __builtin_amdgcn_mfma_f32_16x16x32_bf16(a[cc], bz, az, 0, 0, 0);
            an = __builtin_amdgcn_mfma_f32_16x16x32_bf16(a[cc], bn, an, 0, 0, 0);
            ah = __builtin_amdgcn_mfma_f32_16x16x32_bf16(a[cc], bh, ah, 0, 0, 0);
        }
        __syncthreads();   // (j,1) landed; all waves done with buf0

        // ---- phase 2j+1: stage (j+1,0)->buf0 (if any), compute half1 from buf1 ----
        if (j < 7) {
#pragma unroll
            for (int i = 0; i < 3; ++i) {
                int q = i * 8 + wave;
                GLDS(srcj + 24576 + (size_t)q * 512 + lane * 8, &Bs[0][q * 512]);
            }
        }
#pragma unroll
        for (int cc = 0; cc < 6; ++cc) {
            const __bf16* Bp = &Bs[1][(cc * 4 + lq) * 512 + lm * 8];
            bf16x8 br = *(const bf16x8*)(Bp);
            bf16x8 bz = *(const bf16x8*)(Bp + 128);
            bf16x8 bn = *(const bf16x8*)(Bp + 256);
            bf16x8 bh = *(const bf16x8*)(Bp + 384);
            ar = __builtin_amdgcn_mfma_f32_16x16x32_bf16(a[6 + cc], br, ar, 0, 0, 0);
            az = __builtin_amdgcn_mfma_f32_16x16x32_bf16(a[6 + cc], bz, az, 0, 0, 0);
            an = __builtin_amdgcn_mfma_f32_16x16x32_bf16(a[6 + cc], bn, an, 0, 0, 0);
            ah = __builtin_amdgcn_mfma_f32_16x16x32_bf16(a[6 + cc], bh, ah, 0, 0, 0);
        }
        // ---- epilogue for j (registers + global only) ----
        float cbr = b512[d], cbz = b512[128 + d], cbn = b512[256 + d], cbh = b512[384 + d];
        float hv[4] = {h0, h1, h2, h3};
#pragma unroll
        for (int i = 0; i < 4; ++i) {
            int row = rb + i;
            if (row >= NN) continue;
            float pr  = ar[i] + cbr;
            float pz  = az[i] + cbz;
            float pin = an[i] + cbn;
            float phn = ah[i] + cbh;
            float r = fast_sigmoid(pr);
            float z = fast_sigmoid(pz);
            float nv = fast_tanh(pin + r * phn);
            float hnew = (1.f - z) * nv + z * hv[i];
            hf[(size_t)row * DD + d] = hnew;
            hbc[(size_t)row * DD + d] = (__bf16)hnew;
        }
        __syncthreads();   // (j+1,0) landed; all waves done with buf1
    }
}

// ================= readout =================
__global__ void attn_kernel(const float* __restrict__ hf, const float* __restrict__ w_gate,
                            const float* __restrict__ b_gate, float* __restrict__ attn) {
    int node = blockIdx.x * 4 + (threadIdx.x >> 6);
    int lane = threadIdx.x & 63;
    if (node >= NN) return;
    size_t base = (size_t)node * DD;
    float s = hf[base + lane * 2] * w_gate[lane * 2]
            + hf[base + lane * 2 + 1] * w_gate[lane * 2 + 1];
    for (int off = 32; off; off >>= 1) s += __shfl_down(s, off);
    if (lane == 0) attn[node] = 1.f / (1.f + expf(-(s + b_gate[0])));
}

__global__ void segsum_kernel(const int* __restrict__ goff, const float* __restrict__ attn,
                              const float* __restrict__ hf, float* __restrict__ sg,
                              float* __restrict__ asumg) {
    int g = blockIdx.x;
    int d = threadIdx.x;
    int beg = goff[g], end = goff[g + 1];
    float s0 = 0.f, s1 = 0.f, s2 = 0.f, s3 = 0.f, asum = 0.f;
    int i = beg;
    for (; i + 3 < end; i += 4) {
        float a0 = attn[i], a1 = attn[i + 1], a2 = attn[i + 2], a3 = attn[i + 3];
        float v0 = hf[(size_t)i * DD + d];
        float v1 = hf[(size_t)(i + 1) * DD + d];
        float v2 = hf[(size_t)(i + 2) * DD + d];
        float v3 = hf[(size_t)(i + 3) * DD + d];
        s0 += a0 * v0; s1 += a1 * v1; s2 += a2 * v2; s3 += a3 * v3;
        if (d == 0) asum += a0 + a1 + a2 + a3;
    }
    for (; i < end; ++i) {
        float a = attn[i];
        s0 += a * hf[(size_t)i * DD + d];
        if (d == 0) asum += a;
    }
    sg[g * DD + d] = s0 + s1 + s2 + s3;
    if (d == 0) asumg[g] = asum;
}

__global__ void readout_kernel(const float* __restrict__ sg, const float* __restrict__ asumg,
                               const float* __restrict__ W_g, const float* __restrict__ b_g,
                               float* __restrict__ hgraph) {
    int g = blockIdx.x;
    int m = threadIdx.x;
    float acc = asumg[g] * b_g[m];
    for (int d = 0; d < DD; ++d) acc += sg[g * DD + d] * W_g[d * GHID + m];
    hgraph[g * GHID + m] = acc;
}

// ================= launch =================
extern "C" void kernel_launch(void* const* d_in, const int* in_sizes, int n_in,
                              void* d_out, int out_size, void* d_ws, size_t ws_size,
                              hipStream_t stream) {
    const int*   node_types = (const int*)d_in[0];
    const int*   edge_src   = (const int*)d_in[1];
    const int*   edge_dst   = (const int*)d_in[2];
    const int*   edge_type  = (const int*)d_in[3];
    const int*   node2graph = (const int*)d_in[4];
    const float* emb        = (const float*)d_in[5];
    const float* W_msg      = (const float*)d_in[6];
    const float* b_msg      = (const float*)d_in[7];
    const float* W_ih       = (const float*)d_in[8];
    const float* W_hh       = (const float*)d_in[9];
    const float* b_ih       = (const float*)d_in[10];
    const float* b_hh       = (const float*)d_in[11];
    const float* w_gate     = (const float*)d_in[12];
    const float* b_gate     = (const float*)d_in[13];
    const float* W_g        = (const float*)d_in[14];
    const float* b_g        = (const float*)d_in[15];

    float* hf     = (float*)d_out;
    float* hgraph = hf + (size_t)NN * DD;

    char* ws = (char*)d_ws;
    size_t off = 0;
    auto alloc = [&](size_t bytes) -> char* {
        char* p = ws + off;
        off += (bytes + 255) & ~(size_t)255;
        return p;
    };
    __bf16* X       = (__bf16*)alloc((size_t)NN * 512 * 2);   // 51.2 MB
    __bf16* hbc     = (__bf16*)alloc((size_t)NN * DD * 2);    // 12.8 MB compact h
    __bf16* WK      = (__bf16*)alloc((size_t)16 * 4 * 256 * 8 * 2);
    __bf16* WB      = (__bf16*)alloc((size_t)12 * 4 * 512 * 8 * 2);
    float*  b512    = (float*)alloc(512 * 4);
    float*  attn    = (float*)alloc((size_t)NN * 4);
    float*  sg      = (float*)alloc((size_t)NG * DD * 4);
    float*  asumg   = (float*)alloc((size_t)NG * 4);
    int*    counts  = (int*)alloc((size_t)(NKEY + 1) * 4);
    int*    offsets = (int*)alloc((size_t)(NKEY + 1) * 4);
    int*    cursor  = (int*)alloc((size_t)(NKEY + 1) * 4);
    int*    bsum    = (int*)alloc((size_t)1024 * 4);
    int*    elist   = (int*)alloc((size_t)NE * 4);
    int*    gcounts = (int*)alloc((size_t)(NG + 1) * 4);
    int*    goff    = (int*)alloc((size_t)(NG + 1) * 4);

    hipMemsetAsync(counts, 0, (NKEY + 1) * 4, stream);
    hipMemsetAsync(gcounts, 0, (NG + 1) * 4, stream);

    build_all<<<768, 256, 0, stream>>>(W_msg, W_ih, W_hh, b_ih, b_hh, WK, WB, b512);
    embed_kernel<<<(NN * DD + 255) / 256, 256, 0, stream>>>(node_types, emb, hf, hbc);

    int nbE = (NKEY + 255) / 256;
    hist_kernel<<<(NE + 255) / 256, 256, 0, stream>>>(edge_src, edge_type, counts);
    scan1<<<nbE, 256, 0, stream>>>(counts, offsets, bsum, NKEY);
    scan2<<<1, 1024, 0, stream>>>(bsum, nbE, offsets, NKEY);
    scan3<<<nbE, 256, 0, stream>>>(offsets, bsum, cursor, NKEY);
    fill_kernel<<<(NE + 255) / 256, 256, 0, stream>>>(edge_src, edge_dst, edge_type, cursor, elist);

    ghist_kernel<<<(NN + 255) / 256, 256, 0, stream>>>(node2graph, gcounts);
    gscan<<<1, 512, 0, stream>>>(gcounts, goff);

    int rt2 = (NN + 127) / 128;  // 391
    for (int p = 0; p < NPASS; ++p) {
        agg4<<<(NN + 3) / 4, 256, 0, stream>>>(offsets, elist, hbc, X);
        msgs_gru<<<rt2, 512, 0, stream>>>(X, WK, b_msg, offsets, WB, b512, hf, hbc);
    }

    attn_kernel<<<(NN + 3) / 4, 256, 0, stream>>>(hf, w_gate, b_gate, attn);
    segsum_kernel<<<NG, 128, 0, stream>>>(goff, attn, hf, sg, asumg);
    readout_kernel<<<NG, GHID, 0, stream>>>(sg, asumg, W_g, b_g, hgraph);
}

// Round 16
// 613.434 us; speedup vs baseline: 1.3476x; 1.0318x over previous
//
#include <hip/hip_runtime.h>
#include <hip/hip_bf16.h>

#define NN 50000
#define NE 800000
#define NG 512
#define DD 128
#define MM 256
#define TT 4
#define NPASS 4
#define GHID 256
#define NKEY (NN * TT)          // CSR keys: src*4 + type

typedef __bf16 bf16x2 __attribute__((ext_vector_type(2)));
typedef __bf16 bf16x4 __attribute__((ext_vector_type(4)));
typedef __bf16 bf16x8 __attribute__((ext_vector_type(8)));
typedef float f32x4 __attribute__((ext_vector_type(4)));

__device__ __forceinline__ float fast_sigmoid(float x) {
    return __builtin_amdgcn_rcpf(1.f + __expf(-x));
}
__device__ __forceinline__ float fast_tanh(float x) {
    float e2 = __expf(2.f * x);
    return 1.f - 2.f * __builtin_amdgcn_rcpf(e2 + 1.f);
}

#define GLDS(SRC, DST) \
    __builtin_amdgcn_global_load_lds( \
        (const __attribute__((address_space(1))) unsigned int*)(SRC), \
        (__attribute__((address_space(3))) unsigned int*)(DST), 16, 0, 0)

// ================= setup: weights + biases + embedding in ONE dispatch =================
// grid covers NN*DD threads; sub-ranges also build WK/WB/b512.
__global__ void build_all(const float* __restrict__ W_msg,
                          const float* __restrict__ W_ih, const float* __restrict__ W_hh,
                          const float* __restrict__ b_ih, const float* __restrict__ b_hh,
                          const int* __restrict__ node_types, const float* __restrict__ emb,
                          __bf16* __restrict__ WK, __bf16* __restrict__ WB,
                          float* __restrict__ b512,
                          float* __restrict__ hf, __bf16* __restrict__ hbc) {
    int i = blockIdx.x * 256 + threadIdx.x;
    if (i < NN * DD) {                         // embedding
        int node = i >> 7;
        float v = emb[node_types[node] * DD + (i & 127)];
        hf[i] = v;
        hbc[i] = (__bf16)v;
    }
    if (i < 16 * 4 * 256 * 8) {                // WK
        int j = i & 7, col = (i >> 3) & 255, g = i >> 11; // g=c*4+lq
        int k = g * 8 + j;
        WK[i] = (__bf16)W_msg[k * 256 + col];
    }
    if (i < 8 * 12 * 4 * 4 * 16 * 8) {         // WB (j-major + pi K-permutation)
        int low = i & 127;
        int lm = low >> 3, e = low & 7;
        int rest = i >> 7;
        int g  = rest & 3;
        int lq = (rest >> 2) & 3;
        int jc = rest >> 4;          // j*12 + c
        int c  = jc % 12;
        int j  = jc / 12;
        int k   = (c * 4 + lq) * 8 + e;     // 0..383
        int col = g * 128 + j * 16 + lm;    // 0..511
        int korig = k;
        if (k < 256) {                      // pi_inv: k=(c2,lq2,e2) -> col=nt*16+lq2*4+i2
            int c2 = k >> 5, lq2 = (k >> 3) & 3, e2 = k & 7;
            int nt = c2 * 2 + (e2 >> 2), i2 = e2 & 3;
            korig = nt * 16 + lq2 * 4 + i2;
        }
        float v = 0.f;
        if (col < 256) {
            v = (k < 256) ? W_ih[col * 256 + korig] : W_hh[col * 128 + (k - 256)];
        } else if (col < 384) {
            if (k < 256) v = W_ih[col * 256 + korig];
        } else {
            if (k >= 256) v = W_hh[(col - 128) * 128 + (k - 256)];
        }
        WB[i] = (__bf16)v;
    }
    if (i < 512) {                             // b512
        float v;
        if (i < 256) v = b_ih[i] + b_hh[i];
        else if (i < 384) v = b_ih[i];
        else v = b_hh[i - 128];
        b512[i] = v;
    }
}

// ================= CSR build: edge histogram + graph histogram in one dispatch ==========
__global__ void hist_kernel(const int* __restrict__ src, const int* __restrict__ et,
                            const int* __restrict__ n2g,
                            int* __restrict__ counts, int* __restrict__ gcounts) {
    int e = blockIdx.x * 256 + threadIdx.x;
    if (e < NE) atomicAdd(&counts[src[e] * TT + et[e]], 1);
    if (e < NN) atomicAdd(&gcounts[n2g[e]], 1);
}

__global__ void scan1(const int* __restrict__ counts, int* __restrict__ offsets,
                      int* __restrict__ bsum, int n) {
    __shared__ int sm[256];
    int i = blockIdx.x * 256 + threadIdx.x;
    int v = (i < n) ? counts[i] : 0;
    sm[threadIdx.x] = v;
    __syncthreads();
    for (int off = 1; off < 256; off <<= 1) {
        int t = (threadIdx.x >= off) ? sm[threadIdx.x - off] : 0;
        __syncthreads();
        sm[threadIdx.x] += t;
        __syncthreads();
    }
    if (i < n) offsets[i] = sm[threadIdx.x] - v;
    if (threadIdx.x == 255) bsum[blockIdx.x] = sm[255];
}

// block-sum scan (main CSR) + appended 512-entry graph-offset scan
__global__ void scan2(int* __restrict__ bsum, int nb, int* __restrict__ offsets, int n,
                      const int* __restrict__ gcounts, int* __restrict__ goff) {
    __shared__ int sm[1024];
    __shared__ int sg2[512];
    int t = threadIdx.x;
    int v = (t < nb) ? bsum[t] : 0;
    sm[t] = v;
    __syncthreads();
    for (int off = 1; off < 1024; off <<= 1) {
        int x = (t >= off) ? sm[t - off] : 0;
        __syncthreads();
        sm[t] += x;
        __syncthreads();
    }
    if (t < nb) bsum[t] = sm[t] - v;
    if (t == 1023) offsets[n] = sm[1023];
    // ---- graph-offset scan (512 entries) ----
    int gv = (t < 512) ? gcounts[t] : 0;
    if (t < 512) sg2[t] = gv;
    __syncthreads();
    for (int off = 1; off < 512; off <<= 1) {
        int x = (t >= off && t < 512) ? sg2[t - off] : 0;
        __syncthreads();
        if (t < 512) sg2[t] += x;
        __syncthreads();
    }
    if (t < 512) goff[t] = sg2[t] - gv;
    if (t == 511) goff[512] = sg2[511];
}

__global__ void scan3(int* __restrict__ offsets, const int* __restrict__ bsum,
                      int* __restrict__ cursor, int n) {
    int i = blockIdx.x * 256 + threadIdx.x;
    if (i < n) {
        int o = offsets[i] + bsum[blockIdx.x];
        offsets[i] = o;
        if (cursor) cursor[i] = o;
    }
}

__global__ void fill_kernel(const int* __restrict__ src, const int* __restrict__ dst,
                            const int* __restrict__ et, int* __restrict__ cursor,
                            int* __restrict__ elist) {
    int e = blockIdx.x * 256 + threadIdx.x;
    if (e >= NE) return;
    int pos = atomicAdd(&cursor[src[e] * TT + et[e]], 1);
    elist[pos] = dst[e];
}

// ================= aggregation: wave per SRC ROW (all 4 types), branchless batch-0 =====
__global__ void agg4(const int* __restrict__ offsets, const int* __restrict__ elist,
                     const __bf16* __restrict__ hbc, __bf16* __restrict__ X) {
    int row = blockIdx.x * 4 + (threadIdx.x >> 6);
    if (row >= NN) return;
    int lane = threadIdx.x & 63;
    const __bf16* hb = hbc + lane * 2;
    int ob = row * TT;
    int o0 = __builtin_amdgcn_readfirstlane(offsets[ob]);
    int o1 = __builtin_amdgcn_readfirstlane(offsets[ob + 1]);
    int o2 = __builtin_amdgcn_readfirstlane(offsets[ob + 2]);
    int o3 = __builtin_amdgcn_readfirstlane(offsets[ob + 3]);
    int o4 = __builtin_amdgcn_readfirstlane(offsets[ob + 4]);
    int begs[4] = {o0, o1, o2, o3};
    int ends[4] = {o1, o2, o3, o4};

    float ax[4] = {0.f, 0.f, 0.f, 0.f};
    float ay[4] = {0.f, 0.f, 0.f, 0.f};

    // ---- batch 0: 8 clamped gathers x 4 types, ALL issued before any accumulate ----
    bf16x2 v[4][8];
    int nb[4];
#pragma unroll
    for (int t = 0; t < 4; ++t) {
        int beg = begs[t], end = ends[t];
        nb[t] = end - beg;
        int e1 = end - 1;
        if (e1 < 0) e1 = 0;
        int idx[8];
#pragma unroll
        for (int k = 0; k < 8; ++k) {
            int p = beg + k; if (p > e1) p = e1;
            idx[k] = elist[p];
        }
#pragma unroll
        for (int k = 0; k < 8; ++k)
            v[t][k] = *(const bf16x2*)(hb + (size_t)idx[k] * DD);
    }
#pragma unroll
    for (int t = 0; t < 4; ++t) {
#pragma unroll
        for (int k = 0; k < 8; ++k) {
            float m = (nb[t] > k) ? 1.f : 0.f;
            ax[t] += m * (float)v[t][k].x;
            ay[t] += m * (float)v[t][k].y;
        }
    }

    // ---- tails (deg > 8 per type, rare) ----
#pragma unroll
    for (int t = 0; t < 4; ++t) {
        int end = ends[t];
        for (int base = begs[t] + 8; base < end; base += 8) {
            int nb2 = end - base; if (nb2 > 8) nb2 = 8;
            int e1 = end - 1;
            int idx[8];
#pragma unroll
            for (int k = 0; k < 8; ++k) {
                int p = base + k; if (p > e1) p = e1;
                idx[k] = elist[p];
            }
            bf16x2 tv[8];
#pragma unroll
            for (int k = 0; k < 8; ++k)
                tv[k] = *(const bf16x2*)(hb + (size_t)idx[k] * DD);
#pragma unroll
            for (int k = 0; k < 8; ++k) {
                float m = (nb2 > k) ? 1.f : 0.f;
                ax[t] += m * (float)tv[k].x;
                ay[t] += m * (float)tv[k].y;
            }
        }
    }

#pragma unroll
    for (int t = 0; t < 4; ++t) {
        bf16x2 o;
        o.x = (__bf16)ax[t];
        o.y = (__bf16)ay[t];
        *(bf16x2*)(X + (size_t)(ob + t) * 128 + lane * 2) = o;
    }
}

// ================= FUSED msgs GEMM + GRU GEMM (register handoff, 8-wave block) ======
// byte-exact R15 (632.9 us) version.
__global__ __launch_bounds__(512, 4)
void msgs_gru(const __bf16* __restrict__ X, const __bf16* __restrict__ WK,
              const float* __restrict__ b_msg, const int* __restrict__ offsets,
              const __bf16* __restrict__ WBj, const float* __restrict__ b512,
              float* __restrict__ hf, __bf16* __restrict__ hbc) {
    __shared__ __bf16 Bs[2][12288];   // 48 KB total
    int tid = threadIdx.x, wave = tid >> 6, lane = tid & 63;
    int lm = lane & 15, lq = lane >> 4;
    int r0 = blockIdx.x * 128 + wave * 16;
    int arow = r0 + lm; if (arow >= NN) arow = NN - 1;

    bf16x8 a[12];   // phase-B A-fragments: [0..7]=msgs, [8..11]=h

    // ---------------- phase A: M = relu(X @ WK + deg-bias), swapped operands ----------------
    {
        const __bf16* Ap = X + (size_t)arow * 512 + lq * 8;
#pragma unroll
        for (int i = 0; i < 2; ++i) {
            int q = i * 8 + wave;
            GLDS(WK + (size_t)q * 512 + lane * 8, &Bs[0][q * 512]);
        }
        bf16x8 acur = *(const bf16x8*)(Ap);
        f32x4 acc[16] = {};
        __syncthreads();    // stage 0 landed

#pragma unroll 1
        for (int c = 0; c < 16; ++c) {
            int cur = c & 1;
            bf16x8 anext = acur;
            if (c < 15) {
                const __bf16* src = WK + (size_t)(c + 1) * 8192;
#pragma unroll
                for (int i = 0; i < 2; ++i) {
                    int q = i * 8 + wave;
                    GLDS(src + (size_t)q * 512 + lane * 8, &Bs[cur ^ 1][q * 512]);
                }
                anext = *(const bf16x8*)(Ap + (c + 1) * 32);
            }
#pragma unroll
            for (int nt = 0; nt < 16; ++nt) {
                bf16x8 b = *(const bf16x8*)&Bs[cur][((size_t)lq * 256 + nt * 16 + lm) * 8];
                // SWAPPED: A = WK frag, B = X frag  ->  acc[nt] = M^T tile
                acc[nt] = __builtin_amdgcn_mfma_f32_16x16x32_bf16(b, acur, acc[nt], 0, 0, 0);
            }
            __syncthreads();
            acur = anext;
        }
        // epilogue A (registers only): bias by row-lm degrees, relu, pack to bf16x8
        int ob2 = arow * TT;
        int q0 = offsets[ob2], q1 = offsets[ob2 + 1], q2 = offsets[ob2 + 2],
            q3 = offsets[ob2 + 3], q4 = offsets[ob2 + 4];
        float n0 = (float)(q1 - q0), n1 = (float)(q2 - q1),
              n2 = (float)(q3 - q2), n3 = (float)(q4 - q3);
#pragma unroll
        for (int c = 0; c < 8; ++c) {
#pragma unroll
            for (int e = 0; e < 8; ++e) {
                int nt = c * 2 + (e >> 2), ii = e & 3;
                int col = nt * 16 + lq * 4 + ii;
                float bias = n0 * b_msg[col] + n1 * b_msg[MM + col]
                           + n2 * b_msg[2 * MM + col] + n3 * b_msg[3 * MM + col];
                a[c][e] = (__bf16)fmaxf(acc[nt][ii] + bias, 0.f);
            }
        }
    }

    // ---------------- phase B: GRU ----------------
#pragma unroll
    for (int i = 0; i < 3; ++i) {
        int q = i * 8 + wave;
        GLDS(WBj + (size_t)q * 512 + lane * 8, &Bs[0][q * 512]);
    }
    {
        const __bf16* hp = hbc + (size_t)arow * DD + lq * 8;
#pragma unroll
        for (int c2 = 0; c2 < 4; ++c2)
            a[8 + c2] = *(const bf16x8*)(hp + c2 * 32);
    }
    __syncthreads();   // (0,0) landed

#pragma unroll 1
    for (int j = 0; j < 8; ++j) {
        const __bf16* srcj = WBj + (size_t)j * 24576;
        int d = j * 16 + lm;
        int rb = r0 + lq * 4;
        f32x4 ar = {}, az = {}, an = {}, ah = {};

        // ---- phase 2j: stage (j,1)->buf1, prefetch hold, compute half0 from buf0 ----
#pragma unroll
        for (int i = 0; i < 3; ++i) {
            int q = i * 8 + wave;
            GLDS(srcj + 12288 + (size_t)q * 512 + lane * 8, &Bs[1][q * 512]);
        }
        float h0 = hf[(size_t)(rb + 0 < NN ? rb + 0 : NN - 1) * DD + d];
        float h1 = hf[(size_t)(rb + 1 < NN ? rb + 1 : NN - 1) * DD + d];
        float h2 = hf[(size_t)(rb + 2 < NN ? rb + 2 : NN - 1) * DD + d];
        float h3 = hf[(size_t)(rb + 3 < NN ? rb + 3 : NN - 1) * DD + d];
#pragma unroll
        for (int cc = 0; cc < 6; ++cc) {
            const __bf16* Bp = &Bs[0][(cc * 4 + lq) * 512 + lm * 8];
            bf16x8 br = *(const bf16x8*)(Bp);
            bf16x8 bz = *(const bf16x8*)(Bp + 128);
            bf16x8 bn = *(const bf16x8*)(Bp + 256);
            bf16x8 bh = *(const bf16x8*)(Bp + 384);
            ar = __builtin_amdgcn_mfma_f32_16x16x32_bf16(a[cc], br, ar, 0, 0, 0);
            az = __builtin_amdgcn_mfma_f32_16x16x32_bf16(a[cc], bz, az, 0, 0, 0);
            an = __builtin_amdgcn_mfma_f32_16x16x32_bf16(a[cc], bn, an, 0, 0, 0);
            ah = __builtin_amdgcn_mfma_f32_16x16x32_bf16(a[cc], bh, ah, 0, 0, 0);
        }
        __syncthreads();   // (j,1) landed; all waves done with buf0

        // ---- phase 2j+1: stage (j+1,0)->buf0 (if any), compute half1 from buf1 ----
        if (j < 7) {
#pragma unroll
            for (int i = 0; i < 3; ++i) {
                int q = i * 8 + wave;
                GLDS(srcj + 24576 + (size_t)q * 512 + lane * 8, &Bs[0][q * 512]);
            }
        }
#pragma unroll
        for (int cc = 0; cc < 6; ++cc) {
            const __bf16* Bp = &Bs[1][(cc * 4 + lq) * 512 + lm * 8];
            bf16x8 br = *(const bf16x8*)(Bp);
            bf16x8 bz = *(const bf16x8*)(Bp + 128);
            bf16x8 bn = *(const bf16x8*)(Bp + 256);
            bf16x8 bh = *(const bf16x8*)(Bp + 384);
            ar = __builtin_amdgcn_mfma_f32_16x16x32_bf16(a[6 + cc], br, ar, 0, 0, 0);
            az = __builtin_amdgcn_mfma_f32_16x16x32_bf16(a[6 + cc], bz, az, 0, 0, 0);
            an = __builtin_amdgcn_mfma_f32_16x16x32_bf16(a[6 + cc], bn, an, 0, 0, 0);
            ah = __builtin_amdgcn_mfma_f32_16x16x32_bf16(a[6 + cc], bh, ah, 0, 0, 0);
        }
        // ---- epilogue for j (registers + global only) ----
        float cbr = b512[d], cbz = b512[128 + d], cbn = b512[256 + d], cbh = b512[384 + d];
        float hv[4] = {h0, h1, h2, h3};
#pragma unroll
        for (int i = 0; i < 4; ++i) {
            int row = rb + i;
            if (row >= NN) continue;
            float pr  = ar[i] + cbr;
            float pz  = az[i] + cbz;
            float pin = an[i] + cbn;
            float phn = ah[i] + cbh;
            float r = fast_sigmoid(pr);
            float z = fast_sigmoid(pz);
            float nv = fast_tanh(pin + r * phn);
            float hnew = (1.f - z) * nv + z * hv[i];
            hf[(size_t)row * DD + d] = hnew;
            hbc[(size_t)row * DD + d] = (__bf16)hnew;
        }
        __syncthreads();   // (j+1,0) landed; all waves done with buf1
    }
}

// ================= readout =================
__global__ void attn_kernel(const float* __restrict__ hf, const float* __restrict__ w_gate,
                            const float* __restrict__ b_gate, float* __restrict__ attn) {
    int node = blockIdx.x * 4 + (threadIdx.x >> 6);
    int lane = threadIdx.x & 63;
    if (node >= NN) return;
    size_t base = (size_t)node * DD;
    float s = hf[base + lane * 2] * w_gate[lane * 2]
            + hf[base + lane * 2 + 1] * w_gate[lane * 2 + 1];
    for (int off = 32; off; off >>= 1) s += __shfl_down(s, off);
    if (lane == 0) attn[node] = 1.f / (1.f + expf(-(s + b_gate[0])));
}

// segsum + readout fused: block g computes sg in LDS, then applies W_g directly.
__global__ void segsum_readout(const int* __restrict__ goff, const float* __restrict__ attn,
                               const float* __restrict__ hf, const float* __restrict__ W_g,
                               const float* __restrict__ b_g, float* __restrict__ hgraph) {
    __shared__ float sgs[DD];
    __shared__ float asums;
    int g = blockIdx.x;
    int d = threadIdx.x;
    int beg = goff[g], end = goff[g + 1];
    float s0 = 0.f, s1 = 0.f, s2 = 0.f, s3 = 0.f, asum = 0.f;
    int i = beg;
    for (; i + 3 < end; i += 4) {
        float a0 = attn[i], a1 = attn[i + 1], a2 = attn[i + 2], a3 = attn[i + 3];
        float v0 = hf[(size_t)i * DD + d];
        float v1 = hf[(size_t)(i + 1) * DD + d];
        float v2 = hf[(size_t)(i + 2) * DD + d];
        float v3 = hf[(size_t)(i + 3) * DD + d];
        s0 += a0 * v0; s1 += a1 * v1; s2 += a2 * v2; s3 += a3 * v3;
        if (d == 0) asum += a0 + a1 + a2 + a3;
    }
    for (; i < end; ++i) {
        float a = attn[i];
        s0 += a * hf[(size_t)i * DD + d];
        if (d == 0) asum += a;
    }
    sgs[d] = s0 + s1 + s2 + s3;
    if (d == 0) asums = asum;
    __syncthreads();
    float av = asums;
    float o0 = av * b_g[d];
    float o1 = av * b_g[d + 128];
    for (int k = 0; k < DD; ++k) {
        float sv = sgs[k];
        o0 += sv * W_g[k * GHID + d];
        o1 += sv * W_g[k * GHID + d + 128];
    }
    hgraph[g * GHID + d] = o0;
    hgraph[g * GHID + d + 128] = o1;
}

// ================= launch =================
extern "C" void kernel_launch(void* const* d_in, const int* in_sizes, int n_in,
                              void* d_out, int out_size, void* d_ws, size_t ws_size,
                              hipStream_t stream) {
    const int*   node_types = (const int*)d_in[0];
    const int*   edge_src   = (const int*)d_in[1];
    const int*   edge_dst   = (const int*)d_in[2];
    const int*   edge_type  = (const int*)d_in[3];
    const int*   node2graph = (const int*)d_in[4];
    const float* emb        = (const float*)d_in[5];
    const float* W_msg      = (const float*)d_in[6];
    const float* b_msg      = (const float*)d_in[7];
    const float* W_ih       = (const float*)d_in[8];
    const float* W_hh       = (const float*)d_in[9];
    const float* b_ih       = (const float*)d_in[10];
    const float* b_hh       = (const float*)d_in[11];
    const float* w_gate     = (const float*)d_in[12];
    const float* b_gate     = (const float*)d_in[13];
    const float* W_g        = (const float*)d_in[14];
    const float* b_g        = (const float*)d_in[15];

    float* hf     = (float*)d_out;
    float* hgraph = hf + (size_t)NN * DD;

    char* ws = (char*)d_ws;
    size_t off = 0;
    auto alloc = [&](size_t bytes) -> char* {
        char* p = ws + off;
        off += (bytes + 255) & ~(size_t)255;
        return p;
    };
    __bf16* X       = (__bf16*)alloc((size_t)NN * 512 * 2);   // 51.2 MB
    __bf16* hbc     = (__bf16*)alloc((size_t)NN * DD * 2);    // 12.8 MB compact h
    __bf16* WK      = (__bf16*)alloc((size_t)16 * 4 * 256 * 8 * 2);
    __bf16* WB      = (__bf16*)alloc((size_t)12 * 4 * 512 * 8 * 2);
    float*  b512    = (float*)alloc(512 * 4);
    float*  attn    = (float*)alloc((size_t)NN * 4);
    int*    counts  = (int*)alloc((size_t)(NKEY + 1) * 4);
    int*    offsets = (int*)alloc((size_t)(NKEY + 1) * 4);
    int*    cursor  = (int*)alloc((size_t)(NKEY + 1) * 4);
    int*    bsum    = (int*)alloc((size_t)1024 * 4);
    int*    elist   = (int*)alloc((size_t)NE * 4);
    int*    gcounts = (int*)alloc((size_t)(NG + 1) * 4);
    int*    goff    = (int*)alloc((size_t)(NG + 1) * 4);

    hipMemsetAsync(counts, 0, (NKEY + 1) * 4, stream);
    hipMemsetAsync(gcounts, 0, (NG + 1) * 4, stream);

    build_all<<<(NN * DD + 255) / 256, 256, 0, stream>>>(
        W_msg, W_ih, W_hh, b_ih, b_hh, node_types, emb, WK, WB, b512, hf, hbc);

    int nbE = (NKEY + 255) / 256;
    hist_kernel<<<(NE + 255) / 256, 256, 0, stream>>>(edge_src, edge_type, node2graph,
                                                      counts, gcounts);
    scan1<<<nbE, 256, 0, stream>>>(counts, offsets, bsum, NKEY);
    scan2<<<1, 1024, 0, stream>>>(bsum, nbE, offsets, NKEY, gcounts, goff);
    scan3<<<nbE, 256, 0, stream>>>(offsets, bsum, cursor, NKEY);
    fill_kernel<<<(NE + 255) / 256, 256, 0, stream>>>(edge_src, edge_dst, edge_type, cursor, elist);

    int rt2 = (NN + 127) / 128;  // 391
    for (int p = 0; p < NPASS; ++p) {
        agg4<<<(NN + 3) / 4, 256, 0, stream>>>(offsets, elist, hbc, X);
        msgs_gru<<<rt2, 512, 0, stream>>>(X, WK, b_msg, offsets, WB, b512, hf, hbc);
    }

    attn_kernel<<<(NN + 3) / 4, 256, 0, stream>>>(hf, w_gate, b_gate, attn);
    segsum_readout<<<NG, DD, 0, stream>>>(goff, attn, hf, W_g, b_g, hgraph);
}

// Round 17
// 585.749 us; speedup vs baseline: 1.4112x; 1.0473x over previous
//
#include <hip/hip_runtime.h>
#include <hip/hip_bf16.h>

#define NN 50000
#define NE 800000
#define NG 512
#define DD 128
#define MM 256
#define TT 4
#define NPASS 4
#define GHID 256
#define NKEY (NN * TT)          // CSR keys: src*4 + type

typedef __bf16 bf16x2 __attribute__((ext_vector_type(2)));
typedef __bf16 bf16x4 __attribute__((ext_vector_type(4)));
typedef __bf16 bf16x8 __attribute__((ext_vector_type(8)));
typedef float f32x4 __attribute__((ext_vector_type(4)));

__device__ __forceinline__ float fast_sigmoid(float x) {
    return __builtin_amdgcn_rcpf(1.f + __expf(-x));
}
__device__ __forceinline__ float fast_tanh(float x) {
    float e2 = __expf(2.f * x);
    return 1.f - 2.f * __builtin_amdgcn_rcpf(e2 + 1.f);
}

#define GLDS(SRC, DST) \
    __builtin_amdgcn_global_load_lds( \
        (const __attribute__((address_space(1))) unsigned int*)(SRC), \
        (__attribute__((address_space(3))) unsigned int*)(DST), 16, 0, 0)

// ================= setup: weights + biases + embedding in ONE dispatch =================
__global__ void build_all(const float* __restrict__ W_msg,
                          const float* __restrict__ W_ih, const float* __restrict__ W_hh,
                          const float* __restrict__ b_ih, const float* __restrict__ b_hh,
                          const int* __restrict__ node_types, const float* __restrict__ emb,
                          __bf16* __restrict__ WK, __bf16* __restrict__ WB,
                          float* __restrict__ b512,
                          float* __restrict__ hf, __bf16* __restrict__ hbc) {
    int i = blockIdx.x * 256 + threadIdx.x;
    if (i < NN * DD) {                         // embedding
        int node = i >> 7;
        float v = emb[node_types[node] * DD + (i & 127)];
        hf[i] = v;
        hbc[i] = (__bf16)v;
    }
    if (i < 16 * 4 * 256 * 8) {                // WK
        int j = i & 7, col = (i >> 3) & 255, g = i >> 11; // g=c*4+lq
        int k = g * 8 + j;
        WK[i] = (__bf16)W_msg[k * 256 + col];
    }
    if (i < 8 * 12 * 4 * 4 * 16 * 8) {         // WB (j-major + pi K-permutation)
        int low = i & 127;
        int lm = low >> 3, e = low & 7;
        int rest = i >> 7;
        int g  = rest & 3;
        int lq = (rest >> 2) & 3;
        int jc = rest >> 4;          // j*12 + c
        int c  = jc % 12;
        int j  = jc / 12;
        int k   = (c * 4 + lq) * 8 + e;     // 0..383
        int col = g * 128 + j * 16 + lm;    // 0..511
        int korig = k;
        if (k < 256) {                      // pi_inv: k=(c2,lq2,e2) -> col=nt*16+lq2*4+i2
            int c2 = k >> 5, lq2 = (k >> 3) & 3, e2 = k & 7;
            int nt = c2 * 2 + (e2 >> 2), i2 = e2 & 3;
            korig = nt * 16 + lq2 * 4 + i2;
        }
        float v = 0.f;
        if (col < 256) {
            v = (k < 256) ? W_ih[col * 256 + korig] : W_hh[col * 128 + (k - 256)];
        } else if (col < 384) {
            if (k < 256) v = W_ih[col * 256 + korig];
        } else {
            if (k >= 256) v = W_hh[(col - 128) * 128 + (k - 256)];
        }
        WB[i] = (__bf16)v;
    }
    if (i < 512) {                             // b512
        float v;
        if (i < 256) v = b_ih[i] + b_hh[i];
        else if (i < 384) v = b_ih[i];
        else v = b_hh[i - 128];
        b512[i] = v;
    }
}

// ================= CSR build: edge histogram only (graph offsets via gbound) ==========
__global__ void hist_kernel(const int* __restrict__ src, const int* __restrict__ et,
                            int* __restrict__ counts) {
    int e = blockIdx.x * 256 + threadIdx.x;
    if (e < NE) atomicAdd(&counts[src[e] * TT + et[e]], 1);
}

// n2g is SORTED: goff[g] = first index with n2g >= g, via boundary detection. No atomics.
__global__ void gbound(const int* __restrict__ n2g, int* __restrict__ goff) {
    int i = blockIdx.x * 256 + threadIdx.x;
    if (i > NN) return;
    int a = (i < NN) ? n2g[i] : NG;        // sentinel
    int b = (i > 0) ? n2g[i - 1] : -1;
    for (int g = b + 1; g <= a; ++g) goff[g] = i;
}

__global__ void scan1(const int* __restrict__ counts, int* __restrict__ offsets,
                      int* __restrict__ bsum, int n) {
    __shared__ int sm[256];
    int i = blockIdx.x * 256 + threadIdx.x;
    int v = (i < n) ? counts[i] : 0;
    sm[threadIdx.x] = v;
    __syncthreads();
    for (int off = 1; off < 256; off <<= 1) {
        int t = (threadIdx.x >= off) ? sm[threadIdx.x - off] : 0;
        __syncthreads();
        sm[threadIdx.x] += t;
        __syncthreads();
    }
    if (i < n) offsets[i] = sm[threadIdx.x] - v;
    if (threadIdx.x == 255) bsum[blockIdx.x] = sm[255];
}

__global__ void scan2(int* __restrict__ bsum, int nb, int* __restrict__ offsets, int n) {
    __shared__ int sm[1024];
    int t = threadIdx.x;
    int v = (t < nb) ? bsum[t] : 0;
    sm[t] = v;
    __syncthreads();
    for (int off = 1; off < 1024; off <<= 1) {
        int x = (t >= off) ? sm[t - off] : 0;
        __syncthreads();
        sm[t] += x;
        __syncthreads();
    }
    if (t < nb) bsum[t] = sm[t] - v;
    if (t == 1023) offsets[n] = sm[1023];
}

__global__ void scan3(int* __restrict__ offsets, const int* __restrict__ bsum,
                      int* __restrict__ cursor, int n) {
    int i = blockIdx.x * 256 + threadIdx.x;
    if (i < n) {
        int o = offsets[i] + bsum[blockIdx.x];
        offsets[i] = o;
        if (cursor) cursor[i] = o;
    }
}

__global__ void fill_kernel(const int* __restrict__ src, const int* __restrict__ dst,
                            const int* __restrict__ et, int* __restrict__ cursor,
                            int* __restrict__ elist) {
    int e = blockIdx.x * 256 + threadIdx.x;
    if (e >= NE) return;
    int pos = atomicAdd(&cursor[src[e] * TT + et[e]], 1);
    elist[pos] = dst[e];
}

// ================= aggregation: wave per SRC ROW (all 4 types), branchless batch-0 =====
__global__ void agg4(const int* __restrict__ offsets, const int* __restrict__ elist,
                     const __bf16* __restrict__ hbc, __bf16* __restrict__ X) {
    int row = blockIdx.x * 4 + (threadIdx.x >> 6);
    if (row >= NN) return;
    int lane = threadIdx.x & 63;
    const __bf16* hb = hbc + lane * 2;
    int ob = row * TT;
    int o0 = __builtin_amdgcn_readfirstlane(offsets[ob]);
    int o1 = __builtin_amdgcn_readfirstlane(offsets[ob + 1]);
    int o2 = __builtin_amdgcn_readfirstlane(offsets[ob + 2]);
    int o3 = __builtin_amdgcn_readfirstlane(offsets[ob + 3]);
    int o4 = __builtin_amdgcn_readfirstlane(offsets[ob + 4]);
    int begs[4] = {o0, o1, o2, o3};
    int ends[4] = {o1, o2, o3, o4};

    float ax[4] = {0.f, 0.f, 0.f, 0.f};
    float ay[4] = {0.f, 0.f, 0.f, 0.f};

    // ---- batch 0: 8 clamped gathers x 4 types, ALL issued before any accumulate ----
    bf16x2 v[4][8];
    int nb[4];
#pragma unroll
    for (int t = 0; t < 4; ++t) {
        int beg = begs[t], end = ends[t];
        nb[t] = end - beg;
        int e1 = end - 1;
        if (e1 < 0) e1 = 0;
        int idx[8];
#pragma unroll
        for (int k = 0; k < 8; ++k) {
            int p = beg + k; if (p > e1) p = e1;
            idx[k] = elist[p];
        }
#pragma unroll
        for (int k = 0; k < 8; ++k)
            v[t][k] = *(const bf16x2*)(hb + (size_t)idx[k] * DD);
    }
#pragma unroll
    for (int t = 0; t < 4; ++t) {
#pragma unroll
        for (int k = 0; k < 8; ++k) {
            float m = (nb[t] > k) ? 1.f : 0.f;
            ax[t] += m * (float)v[t][k].x;
            ay[t] += m * (float)v[t][k].y;
        }
    }

    // ---- tails (deg > 8 per type, rare) ----
#pragma unroll
    for (int t = 0; t < 4; ++t) {
        int end = ends[t];
        for (int base = begs[t] + 8; base < end; base += 8) {
            int nb2 = end - base; if (nb2 > 8) nb2 = 8;
            int e1 = end - 1;
            int idx[8];
#pragma unroll
            for (int k = 0; k < 8; ++k) {
                int p = base + k; if (p > e1) p = e1;
                idx[k] = elist[p];
            }
            bf16x2 tv[8];
#pragma unroll
            for (int k = 0; k < 8; ++k)
                tv[k] = *(const bf16x2*)(hb + (size_t)idx[k] * DD);
#pragma unroll
            for (int k = 0; k < 8; ++k) {
                float m = (nb2 > k) ? 1.f : 0.f;
                ax[t] += m * (float)tv[k].x;
                ay[t] += m * (float)tv[k].y;
            }
        }
    }

#pragma unroll
    for (int t = 0; t < 4; ++t) {
        bf16x2 o;
        o.x = (__bf16)ax[t];
        o.y = (__bf16)ay[t];
        *(bf16x2*)(X + (size_t)(ob + t) * 128 + lane * 2) = o;
    }
}

// ================= FUSED msgs GEMM + GRU GEMM (register handoff, 8-wave block) ======
__global__ __launch_bounds__(512, 4)
void msgs_gru(const __bf16* __restrict__ X, const __bf16* __restrict__ WK,
              const float* __restrict__ b_msg, const int* __restrict__ offsets,
              const __bf16* __restrict__ WBj, const float* __restrict__ b512,
              float* __restrict__ hf, __bf16* __restrict__ hbc) {
    __shared__ __bf16 Bs[2][12288];   // 48 KB total
    int tid = threadIdx.x, wave = tid >> 6, lane = tid & 63;
    int lm = lane & 15, lq = lane >> 4;
    int r0 = blockIdx.x * 128 + wave * 16;
    int arow = r0 + lm; if (arow >= NN) arow = NN - 1;

    bf16x8 a[12];   // phase-B A-fragments: [0..7]=msgs, [8..11]=h

    // ---------------- phase A: M = relu(X @ WK + deg-bias), swapped operands ----------------
    {
        const __bf16* Ap = X + (size_t)arow * 512 + lq * 8;
#pragma unroll
        for (int i = 0; i < 2; ++i) {
            int q = i * 8 + wave;
            GLDS(WK + (size_t)q * 512 + lane * 8, &Bs[0][q * 512]);
        }
        bf16x8 acur = *(const bf16x8*)(Ap);
        f32x4 acc[16] = {};
        __syncthreads();    // stage 0 landed

#pragma unroll 1
        for (int c = 0; c < 16; ++c) {
            int cur = c & 1;
            bf16x8 anext = acur;
            if (c < 15) {
                const __bf16* src = WK + (size_t)(c + 1) * 8192;
#pragma unroll
                for (int i = 0; i < 2; ++i) {
                    int q = i * 8 + wave;
                    GLDS(src + (size_t)q * 512 + lane * 8, &Bs[cur ^ 1][q * 512]);
                }
                anext = *(const bf16x8*)(Ap + (c + 1) * 32);
            }
#pragma unroll
            for (int nt = 0; nt < 16; ++nt) {
                bf16x8 b = *(const bf16x8*)&Bs[cur][((size_t)lq * 256 + nt * 16 + lm) * 8];
                // SWAPPED: A = WK frag, B = X frag  ->  acc[nt] = M^T tile
                acc[nt] = __builtin_amdgcn_mfma_f32_16x16x32_bf16(b, acur, acc[nt], 0, 0, 0);
            }
            __syncthreads();
            acur = anext;
        }
        // epilogue A (registers only): bias by row-lm degrees, relu, pack to bf16x8
        int ob2 = arow * TT;
        int q0 = offsets[ob2], q1 = offsets[ob2 + 1], q2 = offsets[ob2 + 2],
            q3 = offsets[ob2 + 3], q4 = offsets[ob2 + 4];
        float n0 = (float)(q1 - q0), n1 = (float)(q2 - q1),
              n2 = (float)(q3 - q2), n3 = (float)(q4 - q3);
#pragma unroll
        for (int c = 0; c < 8; ++c) {
#pragma unroll
            for (int e = 0; e < 8; ++e) {
                int nt = c * 2 + (e >> 2), ii = e & 3;
                int col = nt * 16 + lq * 4 + ii;
                float bias = n0 * b_msg[col] + n1 * b_msg[MM + col]
                           + n2 * b_msg[2 * MM + col] + n3 * b_msg[3 * MM + col];
                a[c][e] = (__bf16)fmaxf(acc[nt][ii] + bias, 0.f);
            }
        }
    }

    // ---------------- phase B: GRU ----------------
#pragma unroll
    for (int i = 0; i < 3; ++i) {
        int q = i * 8 + wave;
        GLDS(WBj + (size_t)q * 512 + lane * 8, &Bs[0][q * 512]);
    }
    {
        const __bf16* hp = hbc + (size_t)arow * DD + lq * 8;
#pragma unroll
        for (int c2 = 0; c2 < 4; ++c2)
            a[8 + c2] = *(const bf16x8*)(hp + c2 * 32);
    }
    __syncthreads();   // (0,0) landed

#pragma unroll 1
    for (int j = 0; j < 8; ++j) {
        const __bf16* srcj = WBj + (size_t)j * 24576;
        int d = j * 16 + lm;
        int rb = r0 + lq * 4;
        f32x4 ar = {}, az = {}, an = {}, ah = {};

        // ---- phase 2j: stage (j,1)->buf1, prefetch hold, compute half0 from buf0 ----
#pragma unroll
        for (int i = 0; i < 3; ++i) {
            int q = i * 8 + wave;
            GLDS(srcj + 12288 + (size_t)q * 512 + lane * 8, &Bs[1][q * 512]);
        }
        float h0 = hf[(size_t)(rb + 0 < NN ? rb + 0 : NN - 1) * DD + d];
        float h1 = hf[(size_t)(rb + 1 < NN ? rb + 1 : NN - 1) * DD + d];
        float h2 = hf[(size_t)(rb + 2 < NN ? rb + 2 : NN - 1) * DD + d];
        float h3 = hf[(size_t)(rb + 3 < NN ? rb + 3 : NN - 1) * DD + d];
#pragma unroll
        for (int cc = 0; cc < 6; ++cc) {
            const __bf16* Bp = &Bs[0][(cc * 4 + lq) * 512 + lm * 8];
            bf16x8 br = *(const bf16x8*)(Bp);
            bf16x8 bz = *(const bf16x8*)(Bp + 128);
            bf16x8 bn = *(const bf16x8*)(Bp + 256);
            bf16x8 bh = *(const bf16x8*)(Bp + 384);
            ar = __builtin_amdgcn_mfma_f32_16x16x32_bf16(a[cc], br, ar, 0, 0, 0);
            az = __builtin_amdgcn_mfma_f32_16x16x32_bf16(a[cc], bz, az, 0, 0, 0);
            an = __builtin_amdgcn_mfma_f32_16x16x32_bf16(a[cc], bn, an, 0, 0, 0);
            ah = __builtin_amdgcn_mfma_f32_16x16x32_bf16(a[cc], bh, ah, 0, 0, 0);
        }
        __syncthreads();   // (j,1) landed; all waves done with buf0

        // ---- phase 2j+1: stage (j+1,0)->buf0 (if any), compute half1 from buf1 ----
        if (j < 7) {
#pragma unroll
            for (int i = 0; i < 3; ++i) {
                int q = i * 8 + wave;
                GLDS(srcj + 24576 + (size_t)q * 512 + lane * 8, &Bs[0][q * 512]);
            }
        }
#pragma unroll
        for (int cc = 0; cc < 6; ++cc) {
            const __bf16* Bp = &Bs[1][(cc * 4 + lq) * 512 + lm * 8];
            bf16x8 br = *(const bf16x8*)(Bp);
            bf16x8 bz = *(const bf16x8*)(Bp + 128);
            bf16x8 bn = *(const bf16x8*)(Bp + 256);
            bf16x8 bh = *(const bf16x8*)(Bp + 384);
            ar = __builtin_amdgcn_mfma_f32_16x16x32_bf16(a[6 + cc], br, ar, 0, 0, 0);
            az = __builtin_amdgcn_mfma_f32_16x16x32_bf16(a[6 + cc], bz, az, 0, 0, 0);
            an = __builtin_amdgcn_mfma_f32_16x16x32_bf16(a[6 + cc], bn, an, 0, 0, 0);
            ah = __builtin_amdgcn_mfma_f32_16x16x32_bf16(a[6 + cc], bh, ah, 0, 0, 0);
        }
        // ---- epilogue for j (registers + global only) ----
        float cbr = b512[d], cbz = b512[128 + d], cbn = b512[256 + d], cbh = b512[384 + d];
        float hv[4] = {h0, h1, h2, h3};
#pragma unroll
        for (int i = 0; i < 4; ++i) {
            int row = rb + i;
            if (row >= NN) continue;
            float pr  = ar[i] + cbr;
            float pz  = az[i] + cbz;
            float pin = an[i] + cbn;
            float phn = ah[i] + cbh;
            float r = fast_sigmoid(pr);
            float z = fast_sigmoid(pz);
            float nv = fast_tanh(pin + r * phn);
            float hnew = (1.f - z) * nv + z * hv[i];
            hf[(size_t)row * DD + d] = hnew;
            hbc[(size_t)row * DD + d] = (__bf16)hnew;
        }
        __syncthreads();   // (j+1,0) landed; all waves done with buf1
    }
}

// ================= readout =================
__global__ void attn_kernel(const float* __restrict__ hf, const float* __restrict__ w_gate,
                            const float* __restrict__ b_gate, float* __restrict__ attn) {
    int node = blockIdx.x * 4 + (threadIdx.x >> 6);
    int lane = threadIdx.x & 63;
    if (node >= NN) return;
    size_t base = (size_t)node * DD;
    float s = hf[base + lane * 2] * w_gate[lane * 2]
            + hf[base + lane * 2 + 1] * w_gate[lane * 2 + 1];
    for (int off = 32; off; off >>= 1) s += __shfl_down(s, off);
    if (lane == 0) attn[node] = 1.f / (1.f + expf(-(s + b_gate[0])));
}

// segsum + readout fused: block g computes sg in LDS, then applies W_g directly.
__global__ void segsum_readout(const int* __restrict__ goff, const float* __restrict__ attn,
                               const float* __restrict__ hf, const float* __restrict__ W_g,
                               const float* __restrict__ b_g, float* __restrict__ hgraph) {
    __shared__ float sgs[DD];
    __shared__ float asums;
    int g = blockIdx.x;
    int d = threadIdx.x;
    int beg = goff[g], end = goff[g + 1];
    float s0 = 0.f, s1 = 0.f, s2 = 0.f, s3 = 0.f, asum = 0.f;
    int i = beg;
    for (; i + 3 < end; i += 4) {
        float a0 = attn[i], a1 = attn[i + 1], a2 = attn[i + 2], a3 = attn[i + 3];
        float v0 = hf[(size_t)i * DD + d];
        float v1 = hf[(size_t)(i + 1) * DD + d];
        float v2 = hf[(size_t)(i + 2) * DD + d];
        float v3 = hf[(size_t)(i + 3) * DD + d];
        s0 += a0 * v0; s1 += a1 * v1; s2 += a2 * v2; s3 += a3 * v3;
        if (d == 0) asum += a0 + a1 + a2 + a3;
    }
    for (; i < end; ++i) {
        float a = attn[i];
        s0 += a * hf[(size_t)i * DD + d];
        if (d == 0) asum += a;
    }
    sgs[d] = s0 + s1 + s2 + s3;
    if (d == 0) asums = asum;
    __syncthreads();
    float av = asums;
    float o0 = av * b_g[d];
    float o1 = av * b_g[d + 128];
    for (int k = 0; k < DD; ++k) {
        float sv = sgs[k];
        o0 += sv * W_g[k * GHID + d];
        o1 += sv * W_g[k * GHID + d + 128];
    }
    hgraph[g * GHID + d] = o0;
    hgraph[g * GHID + d + 128] = o1;
}

// ================= launch =================
extern "C" void kernel_launch(void* const* d_in, const int* in_sizes, int n_in,
                              void* d_out, int out_size, void* d_ws, size_t ws_size,
                              hipStream_t stream) {
    const int*   node_types = (const int*)d_in[0];
    const int*   edge_src   = (const int*)d_in[1];
    const int*   edge_dst   = (const int*)d_in[2];
    const int*   edge_type  = (const int*)d_in[3];
    const int*   node2graph = (const int*)d_in[4];
    const float* emb        = (const float*)d_in[5];
    const float* W_msg      = (const float*)d_in[6];
    const float* b_msg      = (const float*)d_in[7];
    const float* W_ih       = (const float*)d_in[8];
    const float* W_hh       = (const float*)d_in[9];
    const float* b_ih       = (const float*)d_in[10];
    const float* b_hh       = (const float*)d_in[11];
    const float* w_gate     = (const float*)d_in[12];
    const float* b_gate     = (const float*)d_in[13];
    const float* W_g        = (const float*)d_in[14];
    const float* b_g        = (const float*)d_in[15];

    float* hf     = (float*)d_out;
    float* hgraph = hf + (size_t)NN * DD;

    char* ws = (char*)d_ws;
    size_t off = 0;
    auto alloc = [&](size_t bytes) -> char* {
        char* p = ws + off;
        off += (bytes + 255) & ~(size_t)255;
        return p;
    };
    __bf16* X       = (__bf16*)alloc((size_t)NN * 512 * 2);   // 51.2 MB
    __bf16* hbc     = (__bf16*)alloc((size_t)NN * DD * 2);    // 12.8 MB compact h
    __bf16* WK      = (__bf16*)alloc((size_t)16 * 4 * 256 * 8 * 2);
    __bf16* WB      = (__bf16*)alloc((size_t)12 * 4 * 512 * 8 * 2);
    float*  b512    = (float*)alloc(512 * 4);
    float*  attn    = (float*)alloc((size_t)NN * 4);
    int*    counts  = (int*)alloc((size_t)(NKEY + 1) * 4);
    int*    offsets = (int*)alloc((size_t)(NKEY + 1) * 4);
    int*    cursor  = (int*)alloc((size_t)(NKEY + 1) * 4);
    int*    bsum    = (int*)alloc((size_t)1024 * 4);
    int*    elist   = (int*)alloc((size_t)NE * 4);
    int*    goff    = (int*)alloc((size_t)(NG + 1) * 4);

    hipMemsetAsync(counts, 0, (NKEY + 1) * 4, stream);

    build_all<<<(NN * DD + 255) / 256, 256, 0, stream>>>(
        W_msg, W_ih, W_hh, b_ih, b_hh, node_types, emb, WK, WB, b512, hf, hbc);

    int nbE = (NKEY + 255) / 256;
    hist_kernel<<<(NE + 255) / 256, 256, 0, stream>>>(edge_src, edge_type, counts);
    scan1<<<nbE, 256, 0, stream>>>(counts, offsets, bsum, NKEY);
    scan2<<<1, 1024, 0, stream>>>(bsum, nbE, offsets, NKEY);
    scan3<<<nbE, 256, 0, stream>>>(offsets, bsum, cursor, NKEY);
    fill_kernel<<<(NE + 255) / 256, 256, 0, stream>>>(edge_src, edge_dst, edge_type, cursor, elist);
    gbound<<<(NN + 256) / 256, 256, 0, stream>>>(node2graph, goff);

    int rt2 = (NN + 127) / 128;  // 391
    for (int p = 0; p < NPASS; ++p) {
        agg4<<<(NN + 3) / 4, 256, 0, stream>>>(offsets, elist, hbc, X);
        msgs_gru<<<rt2, 512, 0, stream>>>(X, WK, b_msg, offsets, WB, b512, hf, hbc);
    }

    attn_kernel<<<(NN + 3) / 4, 256, 0, stream>>>(hf, w_gate, b_gate, attn);
    segsum_readout<<<NG, DD, 0, stream>>>(goff, attn, hf, W_g, b_g, hgraph);
}

// Round 18
// 577.094 us; speedup vs baseline: 1.4324x; 1.0150x over previous
//
#include <hip/hip_runtime.h>
#include <hip/hip_bf16.h>

#define NN 50000
#define NE 800000
#define NG 512
#define DD 128
#define MM 256
#define TT 4
#define NPASS 4
#define GHID 256
#define NKEY (NN * TT)          // CSR keys: src*4 + type

typedef __bf16 bf16x2 __attribute__((ext_vector_type(2)));
typedef __bf16 bf16x4 __attribute__((ext_vector_type(4)));
typedef __bf16 bf16x8 __attribute__((ext_vector_type(8)));
typedef float f32x4 __attribute__((ext_vector_type(4)));

__device__ __forceinline__ float fast_sigmoid(float x) {
    return __builtin_amdgcn_rcpf(1.f + __expf(-x));
}
__device__ __forceinline__ float fast_tanh(float x) {
    float e2 = __expf(2.f * x);
    return 1.f - 2.f * __builtin_amdgcn_rcpf(e2 + 1.f);
}

#define GLDS(SRC, DST) \
    __builtin_amdgcn_global_load_lds( \
        (const __attribute__((address_space(1))) unsigned int*)(SRC), \
        (__attribute__((address_space(3))) unsigned int*)(DST), 16, 0, 0)

// ================= setup: weights + biases + embedding + edge hist + graph bounds ======
// ONE dispatch, disjoint thread ranges, independent buffers.
__global__ void build_all(const float* __restrict__ W_msg,
                          const float* __restrict__ W_ih, const float* __restrict__ W_hh,
                          const float* __restrict__ b_ih, const float* __restrict__ b_hh,
                          const int* __restrict__ node_types, const float* __restrict__ emb,
                          const int* __restrict__ edge_src, const int* __restrict__ edge_type,
                          const int* __restrict__ n2g,
                          __bf16* __restrict__ WK, __bf16* __restrict__ WB,
                          float* __restrict__ b512,
                          float* __restrict__ hf, __bf16* __restrict__ hbc,
                          int* __restrict__ counts, int* __restrict__ goff) {
    int i = blockIdx.x * 256 + threadIdx.x;
    if (i < NN * DD) {                         // embedding
        int node = i >> 7;
        float v = emb[node_types[node] * DD + (i & 127)];
        hf[i] = v;
        hbc[i] = (__bf16)v;
    }
    if (i < NE) {                              // edge histogram
        atomicAdd(&counts[edge_src[i] * TT + edge_type[i]], 1);
    }
    if (i <= NN) {                             // graph offsets (n2g sorted, no atomics)
        int a = (i < NN) ? n2g[i] : NG;        // sentinel
        int b = (i > 0) ? n2g[i - 1] : -1;
        for (int g = b + 1; g <= a; ++g) goff[g] = i;
    }
    if (i < 16 * 4 * 256 * 8) {                // WK
        int j = i & 7, col = (i >> 3) & 255, g = i >> 11; // g=c*4+lq
        int k = g * 8 + j;
        WK[i] = (__bf16)W_msg[k * 256 + col];
    }
    if (i < 8 * 12 * 4 * 4 * 16 * 8) {         // WB (j-major + pi K-permutation)
        int low = i & 127;
        int lm = low >> 3, e = low & 7;
        int rest = i >> 7;
        int g  = rest & 3;
        int lq = (rest >> 2) & 3;
        int jc = rest >> 4;          // j*12 + c
        int c  = jc % 12;
        int j  = jc / 12;
        int k   = (c * 4 + lq) * 8 + e;     // 0..383
        int col = g * 128 + j * 16 + lm;    // 0..511
        int korig = k;
        if (k < 256) {                      // pi_inv: k=(c2,lq2,e2) -> col=nt*16+lq2*4+i2
            int c2 = k >> 5, lq2 = (k >> 3) & 3, e2 = k & 7;
            int nt = c2 * 2 + (e2 >> 2), i2 = e2 & 3;
            korig = nt * 16 + lq2 * 4 + i2;
        }
        float v = 0.f;
        if (col < 256) {
            v = (k < 256) ? W_ih[col * 256 + korig] : W_hh[col * 128 + (k - 256)];
        } else if (col < 384) {
            if (k < 256) v = W_ih[col * 256 + korig];
        } else {
            if (k >= 256) v = W_hh[(col - 128) * 128 + (k - 256)];
        }
        WB[i] = (__bf16)v;
    }
    if (i < 512) {                             // b512
        float v;
        if (i < 256) v = b_ih[i] + b_hh[i];
        else if (i < 384) v = b_ih[i];
        else v = b_hh[i - 128];
        b512[i] = v;
    }
}

__global__ void scan1(const int* __restrict__ counts, int* __restrict__ offsets,
                      int* __restrict__ bsum, int n) {
    __shared__ int sm[256];
    int i = blockIdx.x * 256 + threadIdx.x;
    int v = (i < n) ? counts[i] : 0;
    sm[threadIdx.x] = v;
    __syncthreads();
    for (int off = 1; off < 256; off <<= 1) {
        int t = (threadIdx.x >= off) ? sm[threadIdx.x - off] : 0;
        __syncthreads();
        sm[threadIdx.x] += t;
        __syncthreads();
    }
    if (i < n) offsets[i] = sm[threadIdx.x] - v;
    if (threadIdx.x == 255) bsum[blockIdx.x] = sm[255];
}

__global__ void scan2(int* __restrict__ bsum, int nb, int* __restrict__ offsets, int n) {
    __shared__ int sm[1024];
    int t = threadIdx.x;
    int v = (t < nb) ? bsum[t] : 0;
    sm[t] = v;
    __syncthreads();
    for (int off = 1; off < 1024; off <<= 1) {
        int x = (t >= off) ? sm[t - off] : 0;
        __syncthreads();
        sm[t] += x;
        __syncthreads();
    }
    if (t < nb) bsum[t] = sm[t] - v;
    if (t == 1023) offsets[n] = sm[1023];
}

__global__ void scan3(int* __restrict__ offsets, const int* __restrict__ bsum,
                      int* __restrict__ cursor, int n) {
    int i = blockIdx.x * 256 + threadIdx.x;
    if (i < n) {
        int o = offsets[i] + bsum[blockIdx.x];
        offsets[i] = o;
        if (cursor) cursor[i] = o;
    }
}

__global__ void fill_kernel(const int* __restrict__ src, const int* __restrict__ dst,
                            const int* __restrict__ et, int* __restrict__ cursor,
                            int* __restrict__ elist) {
    int e = blockIdx.x * 256 + threadIdx.x;
    if (e >= NE) return;
    int pos = atomicAdd(&cursor[src[e] * TT + et[e]], 1);
    elist[pos] = dst[e];
}

// ================= aggregation: wave per SRC ROW (all 4 types), branchless batch-0 =====
__global__ void agg4(const int* __restrict__ offsets, const int* __restrict__ elist,
                     const __bf16* __restrict__ hbc, __bf16* __restrict__ X) {
    int row = blockIdx.x * 4 + (threadIdx.x >> 6);
    if (row >= NN) return;
    int lane = threadIdx.x & 63;
    const __bf16* hb = hbc + lane * 2;
    int ob = row * TT;
    int o0 = __builtin_amdgcn_readfirstlane(offsets[ob]);
    int o1 = __builtin_amdgcn_readfirstlane(offsets[ob + 1]);
    int o2 = __builtin_amdgcn_readfirstlane(offsets[ob + 2]);
    int o3 = __builtin_amdgcn_readfirstlane(offsets[ob + 3]);
    int o4 = __builtin_amdgcn_readfirstlane(offsets[ob + 4]);
    int begs[4] = {o0, o1, o2, o3};
    int ends[4] = {o1, o2, o3, o4};

    float ax[4] = {0.f, 0.f, 0.f, 0.f};
    float ay[4] = {0.f, 0.f, 0.f, 0.f};

    // ---- batch 0: 8 clamped gathers x 4 types, ALL issued before any accumulate ----
    bf16x2 v[4][8];
    int nb[4];
#pragma unroll
    for (int t = 0; t < 4; ++t) {
        int beg = begs[t], end = ends[t];
        nb[t] = end - beg;
        int e1 = end - 1;
        if (e1 < 0) e1 = 0;
        int idx[8];
#pragma unroll
        for (int k = 0; k < 8; ++k) {
            int p = beg + k; if (p > e1) p = e1;
            idx[k] = elist[p];
        }
#pragma unroll
        for (int k = 0; k < 8; ++k)
            v[t][k] = *(const bf16x2*)(hb + (size_t)idx[k] * DD);
    }
#pragma unroll
    for (int t = 0; t < 4; ++t) {
#pragma unroll
        for (int k = 0; k < 8; ++k) {
            float m = (nb[t] > k) ? 1.f : 0.f;
            ax[t] += m * (float)v[t][k].x;
            ay[t] += m * (float)v[t][k].y;
        }
    }

    // ---- tails (deg > 8 per type, rare) ----
#pragma unroll
    for (int t = 0; t < 4; ++t) {
        int end = ends[t];
        for (int base = begs[t] + 8; base < end; base += 8) {
            int nb2 = end - base; if (nb2 > 8) nb2 = 8;
            int e1 = end - 1;
            int idx[8];
#pragma unroll
            for (int k = 0; k < 8; ++k) {
                int p = base + k; if (p > e1) p = e1;
                idx[k] = elist[p];
            }
            bf16x2 tv[8];
#pragma unroll
            for (int k = 0; k < 8; ++k)
                tv[k] = *(const bf16x2*)(hb + (size_t)idx[k] * DD);
#pragma unroll
            for (int k = 0; k < 8; ++k) {
                float m = (nb2 > k) ? 1.f : 0.f;
                ax[t] += m * (float)tv[k].x;
                ay[t] += m * (float)tv[k].y;
            }
        }
    }

#pragma unroll
    for (int t = 0; t < 4; ++t) {
        bf16x2 o;
        o.x = (__bf16)ax[t];
        o.y = (__bf16)ay[t];
        *(bf16x2*)(X + (size_t)(ob + t) * 128 + lane * 2) = o;
    }
}

// ================= FUSED msgs GEMM + GRU GEMM (register handoff, 8-wave block) ======
__global__ __launch_bounds__(512, 4)
void msgs_gru(const __bf16* __restrict__ X, const __bf16* __restrict__ WK,
              const float* __restrict__ b_msg, const int* __restrict__ offsets,
              const __bf16* __restrict__ WBj, const float* __restrict__ b512,
              float* __restrict__ hf, __bf16* __restrict__ hbc) {
    __shared__ __bf16 Bs[2][12288];   // 48 KB total
    int tid = threadIdx.x, wave = tid >> 6, lane = tid & 63;
    int lm = lane & 15, lq = lane >> 4;
    int r0 = blockIdx.x * 128 + wave * 16;
    int arow = r0 + lm; if (arow >= NN) arow = NN - 1;

    bf16x8 a[12];   // phase-B A-fragments: [0..7]=msgs, [8..11]=h

    // ---------------- phase A: M = relu(X @ WK + deg-bias), swapped operands ----------------
    {
        const __bf16* Ap = X + (size_t)arow * 512 + lq * 8;
#pragma unroll
        for (int i = 0; i < 2; ++i) {
            int q = i * 8 + wave;
            GLDS(WK + (size_t)q * 512 + lane * 8, &Bs[0][q * 512]);
        }
        bf16x8 acur = *(const bf16x8*)(Ap);
        f32x4 acc[16] = {};
        __syncthreads();    // stage 0 landed

#pragma unroll 1
        for (int c = 0; c < 16; ++c) {
            int cur = c & 1;
            bf16x8 anext = acur;
            if (c < 15) {
                const __bf16* src = WK + (size_t)(c + 1) * 8192;
#pragma unroll
                for (int i = 0; i < 2; ++i) {
                    int q = i * 8 + wave;
                    GLDS(src + (size_t)q * 512 + lane * 8, &Bs[cur ^ 1][q * 512]);
                }
                anext = *(const bf16x8*)(Ap + (c + 1) * 32);
            }
#pragma unroll
            for (int nt = 0; nt < 16; ++nt) {
                bf16x8 b = *(const bf16x8*)&Bs[cur][((size_t)lq * 256 + nt * 16 + lm) * 8];
                // SWAPPED: A = WK frag, B = X frag  ->  acc[nt] = M^T tile
                acc[nt] = __builtin_amdgcn_mfma_f32_16x16x32_bf16(b, acur, acc[nt], 0, 0, 0);
            }
            __syncthreads();
            acur = anext;
        }
        // epilogue A (registers only): bias by row-lm degrees, relu, pack to bf16x8
        int ob2 = arow * TT;
        int q0 = offsets[ob2], q1 = offsets[ob2 + 1], q2 = offsets[ob2 + 2],
            q3 = offsets[ob2 + 3], q4 = offsets[ob2 + 4];
        float n0 = (float)(q1 - q0), n1 = (float)(q2 - q1),
              n2 = (float)(q3 - q2), n3 = (float)(q4 - q3);
#pragma unroll
        for (int c = 0; c < 8; ++c) {
#pragma unroll
            for (int e = 0; e < 8; ++e) {
                int nt = c * 2 + (e >> 2), ii = e & 3;
                int col = nt * 16 + lq * 4 + ii;
                float bias = n0 * b_msg[col] + n1 * b_msg[MM + col]
                           + n2 * b_msg[2 * MM + col] + n3 * b_msg[3 * MM + col];
                a[c][e] = (__bf16)fmaxf(acc[nt][ii] + bias, 0.f);
            }
        }
    }

    // ---------------- phase B: GRU ----------------
#pragma unroll
    for (int i = 0; i < 3; ++i) {
        int q = i * 8 + wave;
        GLDS(WBj + (size_t)q * 512 + lane * 8, &Bs[0][q * 512]);
    }
    {
        const __bf16* hp = hbc + (size_t)arow * DD + lq * 8;
#pragma unroll
        for (int c2 = 0; c2 < 4; ++c2)
            a[8 + c2] = *(const bf16x8*)(hp + c2 * 32);
    }
    __syncthreads();   // (0,0) landed

#pragma unroll 1
    for (int j = 0; j < 8; ++j) {
        const __bf16* srcj = WBj + (size_t)j * 24576;
        int d = j * 16 + lm;
        int rb = r0 + lq * 4;
        f32x4 ar = {}, az = {}, an = {}, ah = {};

        // ---- phase 2j: stage (j,1)->buf1, prefetch hold, compute half0 from buf0 ----
#pragma unroll
        for (int i = 0; i < 3; ++i) {
            int q = i * 8 + wave;
            GLDS(srcj + 12288 + (size_t)q * 512 + lane * 8, &Bs[1][q * 512]);
        }
        float h0 = hf[(size_t)(rb + 0 < NN ? rb + 0 : NN - 1) * DD + d];
        float h1 = hf[(size_t)(rb + 1 < NN ? rb + 1 : NN - 1) * DD + d];
        float h2 = hf[(size_t)(rb + 2 < NN ? rb + 2 : NN - 1) * DD + d];
        float h3 = hf[(size_t)(rb + 3 < NN ? rb + 3 : NN - 1) * DD + d];
#pragma unroll
        for (int cc = 0; cc < 6; ++cc) {
            const __bf16* Bp = &Bs[0][(cc * 4 + lq) * 512 + lm * 8];
            bf16x8 br = *(const bf16x8*)(Bp);
            bf16x8 bz = *(const bf16x8*)(Bp + 128);
            bf16x8 bn = *(const bf16x8*)(Bp + 256);
            bf16x8 bh = *(const bf16x8*)(Bp + 384);
            ar = __builtin_amdgcn_mfma_f32_16x16x32_bf16(a[cc], br, ar, 0, 0, 0);
            az = __builtin_amdgcn_mfma_f32_16x16x32_bf16(a[cc], bz, az, 0, 0, 0);
            an = __builtin_amdgcn_mfma_f32_16x16x32_bf16(a[cc], bn, an, 0, 0, 0);
            ah = __builtin_amdgcn_mfma_f32_16x16x32_bf16(a[cc], bh, ah, 0, 0, 0);
        }
        __syncthreads();   // (j,1) landed; all waves done with buf0

        // ---- phase 2j+1: stage (j+1,0)->buf0 (if any), compute half1 from buf1 ----
        if (j < 7) {
#pragma unroll
            for (int i = 0; i < 3; ++i) {
                int q = i * 8 + wave;
                GLDS(srcj + 24576 + (size_t)q * 512 + lane * 8, &Bs[0][q * 512]);
            }
        }
#pragma unroll
        for (int cc = 0; cc < 6; ++cc) {
            const __bf16* Bp = &Bs[1][(cc * 4 + lq) * 512 + lm * 8];
            bf16x8 br = *(const bf16x8*)(Bp);
            bf16x8 bz = *(const bf16x8*)(Bp + 128);
            bf16x8 bn = *(const bf16x8*)(Bp + 256);
            bf16x8 bh = *(const bf16x8*)(Bp + 384);
            ar = __builtin_amdgcn_mfma_f32_16x16x32_bf16(a[6 + cc], br, ar, 0, 0, 0);
            az = __builtin_amdgcn_mfma_f32_16x16x32_bf16(a[6 + cc], bz, az, 0, 0, 0);
            an = __builtin_amdgcn_mfma_f32_16x16x32_bf16(a[6 + cc], bn, an, 0, 0, 0);
            ah = __builtin_amdgcn_mfma_f32_16x16x32_bf16(a[6 + cc], bh, ah, 0, 0, 0);
        }
        // ---- epilogue for j (registers + global only) ----
        float cbr = b512[d], cbz = b512[128 + d], cbn = b512[256 + d], cbh = b512[384 + d];
        float hv[4] = {h0, h1, h2, h3};
#pragma unroll
        for (int i = 0; i < 4; ++i) {
            int row = rb + i;
            if (row >= NN) continue;
            float pr  = ar[i] + cbr;
            float pz  = az[i] + cbz;
            float pin = an[i] + cbn;
            float phn = ah[i] + cbh;
            float r = fast_sigmoid(pr);
            float z = fast_sigmoid(pz);
            float nv = fast_tanh(pin + r * phn);
            float hnew = (1.f - z) * nv + z * hv[i];
            hf[(size_t)row * DD + d] = hnew;
            hbc[(size_t)row * DD + d] = (__bf16)hnew;
        }
        __syncthreads();   // (j+1,0) landed; all waves done with buf1
    }
}

// ================= readout =================
__global__ void attn_kernel(const float* __restrict__ hf, const float* __restrict__ w_gate,
                            const float* __restrict__ b_gate, float* __restrict__ attn) {
    int node = blockIdx.x * 4 + (threadIdx.x >> 6);
    int lane = threadIdx.x & 63;
    if (node >= NN) return;
    size_t base = (size_t)node * DD;
    float s = hf[base + lane * 2] * w_gate[lane * 2]
            + hf[base + lane * 2 + 1] * w_gate[lane * 2 + 1];
    for (int off = 32; off; off >>= 1) s += __shfl_down(s, off);
    if (lane == 0) attn[node] = 1.f / (1.f + expf(-(s + b_gate[0])));
}

// segsum + readout fused: block g computes sg in LDS, then applies W_g directly.
__global__ void segsum_readout(const int* __restrict__ goff, const float* __restrict__ attn,
                               const float* __restrict__ hf, const float* __restrict__ W_g,
                               const float* __restrict__ b_g, float* __restrict__ hgraph) {
    __shared__ float sgs[DD];
    __shared__ float asums;
    int g = blockIdx.x;
    int d = threadIdx.x;
    int beg = goff[g], end = goff[g + 1];
    float s0 = 0.f, s1 = 0.f, s2 = 0.f, s3 = 0.f, asum = 0.f;
    int i = beg;
    for (; i + 3 < end; i += 4) {
        float a0 = attn[i], a1 = attn[i + 1], a2 = attn[i + 2], a3 = attn[i + 3];
        float v0 = hf[(size_t)i * DD + d];
        float v1 = hf[(size_t)(i + 1) * DD + d];
        float v2 = hf[(size_t)(i + 2) * DD + d];
        float v3 = hf[(size_t)(i + 3) * DD + d];
        s0 += a0 * v0; s1 += a1 * v1; s2 += a2 * v2; s3 += a3 * v3;
        if (d == 0) asum += a0 + a1 + a2 + a3;
    }
    for (; i < end; ++i) {
        float a = attn[i];
        s0 += a * hf[(size_t)i * DD + d];
        if (d == 0) asum += a;
    }
    sgs[d] = s0 + s1 + s2 + s3;
    if (d == 0) asums = asum;
    __syncthreads();
    float av = asums;
    float o0 = av * b_g[d];
    float o1 = av * b_g[d + 128];
    for (int k = 0; k < DD; ++k) {
        float sv = sgs[k];
        o0 += sv * W_g[k * GHID + d];
        o1 += sv * W_g[k * GHID + d + 128];
    }
    hgraph[g * GHID + d] = o0;
    hgraph[g * GHID + d + 128] = o1;
}

// ================= launch =================
extern "C" void kernel_launch(void* const* d_in, const int* in_sizes, int n_in,
                              void* d_out, int out_size, void* d_ws, size_t ws_size,
                              hipStream_t stream) {
    const int*   node_types = (const int*)d_in[0];
    const int*   edge_src   = (const int*)d_in[1];
    const int*   edge_dst   = (const int*)d_in[2];
    const int*   edge_type  = (const int*)d_in[3];
    const int*   node2graph = (const int*)d_in[4];
    const float* emb        = (const float*)d_in[5];
    const float* W_msg      = (const float*)d_in[6];
    const float* b_msg      = (const float*)d_in[7];
    const float* W_ih       = (const float*)d_in[8];
    const float* W_hh       = (const float*)d_in[9];
    const float* b_ih       = (const float*)d_in[10];
    const float* b_hh       = (const float*)d_in[11];
    const float* w_gate     = (const float*)d_in[12];
    const float* b_gate     = (const float*)d_in[13];
    const float* W_g        = (const float*)d_in[14];
    const float* b_g        = (const float*)d_in[15];

    float* hf     = (float*)d_out;
    float* hgraph = hf + (size_t)NN * DD;

    char* ws = (char*)d_ws;
    size_t off = 0;
    auto alloc = [&](size_t bytes) -> char* {
        char* p = ws + off;
        off += (bytes + 255) & ~(size_t)255;
        return p;
    };
    __bf16* X       = (__bf16*)alloc((size_t)NN * 512 * 2);   // 51.2 MB
    __bf16* hbc     = (__bf16*)alloc((size_t)NN * DD * 2);    // 12.8 MB compact h
    __bf16* WK      = (__bf16*)alloc((size_t)16 * 4 * 256 * 8 * 2);
    __bf16* WB      = (__bf16*)alloc((size_t)12 * 4 * 512 * 8 * 2);
    float*  b512    = (float*)alloc(512 * 4);
    float*  attn    = (float*)alloc((size_t)NN * 4);
    int*    counts  = (int*)alloc((size_t)(NKEY + 1) * 4);
    int*    offsets = (int*)alloc((size_t)(NKEY + 1) * 4);
    int*    cursor  = (int*)alloc((size_t)(NKEY + 1) * 4);
    int*    bsum    = (int*)alloc((size_t)1024 * 4);
    int*    elist   = (int*)alloc((size_t)NE * 4);
    int*    goff    = (int*)alloc((size_t)(NG + 1) * 4);

    hipMemsetAsync(counts, 0, (NKEY + 1) * 4, stream);

    build_all<<<(NN * DD + 255) / 256, 256, 0, stream>>>(
        W_msg, W_ih, W_hh, b_ih, b_hh, node_types, emb,
        edge_src, edge_type, node2graph,
        WK, WB, b512, hf, hbc, counts, goff);

    int nbE = (NKEY + 255) / 256;
    scan1<<<nbE, 256, 0, stream>>>(counts, offsets, bsum, NKEY);
    scan2<<<1, 1024, 0, stream>>>(bsum, nbE, offsets, NKEY);
    scan3<<<nbE, 256, 0, stream>>>(offsets, bsum, cursor, NKEY);
    fill_kernel<<<(NE + 255) / 256, 256, 0, stream>>>(edge_src, edge_dst, edge_type, cursor, elist);

    int rt2 = (NN + 127) / 128;  // 391
    for (int p = 0; p < NPASS; ++p) {
        agg4<<<(NN + 3) / 4, 256, 0, stream>>>(offsets, elist, hbc, X);
        msgs_gru<<<rt2, 512, 0, stream>>>(X, WK, b_msg, offsets, WB, b512, hf, hbc);
    }

    attn_kernel<<<(NN + 3) / 4, 256, 0, stream>>>(hf, w_gate, b_gate, attn);
    segsum_readout<<<NG, DD, 0, stream>>>(goff, attn, hf, W_g, b_g, hgraph);
}

// Round 19
// 561.846 us; speedup vs baseline: 1.4713x; 1.0271x over previous
//
#include <hip/hip_runtime.h>
#include <hip/hip_bf16.h>

#define NN 50000
#define NE 800000
#define NG 512
#define DD 128
#define MM 256
#define TT 4
#define NPASS 4
#define GHID 256
#define NKEY (NN * TT)          // CSR keys: src*4 + type

typedef __bf16 bf16x2 __attribute__((ext_vector_type(2)));
typedef __bf16 bf16x4 __attribute__((ext_vector_type(4)));
typedef __bf16 bf16x8 __attribute__((ext_vector_type(8)));
typedef float f32x4 __attribute__((ext_vector_type(4)));

__device__ __forceinline__ float fast_sigmoid(float x) {
    return __builtin_amdgcn_rcpf(1.f + __expf(-x));
}
__device__ __forceinline__ float fast_tanh(float x) {
    float e2 = __expf(2.f * x);
    return 1.f - 2.f * __builtin_amdgcn_rcpf(e2 + 1.f);
}

#define GLDS(SRC, DST) \
    __builtin_amdgcn_global_load_lds( \
        (const __attribute__((address_space(1))) unsigned int*)(SRC), \
        (__attribute__((address_space(3))) unsigned int*)(DST), 16, 0, 0)

// ================= setup: weights + biases + embedding + edge hist + graph bounds ======
// ONE dispatch, disjoint thread ranges, independent buffers.
__global__ void build_all(const float* __restrict__ W_msg,
                          const float* __restrict__ W_ih, const float* __restrict__ W_hh,
                          const float* __restrict__ b_ih, const float* __restrict__ b_hh,
                          const int* __restrict__ node_types, const float* __restrict__ emb,
                          const int* __restrict__ edge_src, const int* __restrict__ edge_type,
                          const int* __restrict__ n2g,
                          __bf16* __restrict__ WK, __bf16* __restrict__ WB,
                          float* __restrict__ b512,
                          float* __restrict__ hf, __bf16* __restrict__ hbc,
                          int* __restrict__ counts, int* __restrict__ goff) {
    int i = blockIdx.x * 256 + threadIdx.x;
    if (i < NN * DD) {                         // embedding
        int node = i >> 7;
        float v = emb[node_types[node] * DD + (i & 127)];
        hf[i] = v;
        hbc[i] = (__bf16)v;
    }
    if (i < NE) {                              // edge histogram
        atomicAdd(&counts[edge_src[i] * TT + edge_type[i]], 1);
    }
    if (i <= NN) {                             // graph offsets (n2g sorted, no atomics)
        int a = (i < NN) ? n2g[i] : NG;        // sentinel
        int b = (i > 0) ? n2g[i - 1] : -1;
        for (int g = b + 1; g <= a; ++g) goff[g] = i;
    }
    if (i < 16 * 4 * 256 * 8) {                // WK
        int j = i & 7, col = (i >> 3) & 255, g = i >> 11; // g=c*4+lq
        int k = g * 8 + j;
        WK[i] = (__bf16)W_msg[k * 256 + col];
    }
    if (i < 8 * 12 * 4 * 4 * 16 * 8) {         // WB (j-major + pi K-permutation)
        int low = i & 127;
        int lm = low >> 3, e = low & 7;
        int rest = i >> 7;
        int g  = rest & 3;
        int lq = (rest >> 2) & 3;
        int jc = rest >> 4;          // j*12 + c
        int c  = jc % 12;
        int j  = jc / 12;
        int k   = (c * 4 + lq) * 8 + e;     // 0..383
        int col = g * 128 + j * 16 + lm;    // 0..511
        int korig = k;
        if (k < 256) {                      // pi_inv: k=(c2,lq2,e2) -> col=nt*16+lq2*4+i2
            int c2 = k >> 5, lq2 = (k >> 3) & 3, e2 = k & 7;
            int nt = c2 * 2 + (e2 >> 2), i2 = e2 & 3;
            korig = nt * 16 + lq2 * 4 + i2;
        }
        float v = 0.f;
        if (col < 256) {
            v = (k < 256) ? W_ih[col * 256 + korig] : W_hh[col * 128 + (k - 256)];
        } else if (col < 384) {
            if (k < 256) v = W_ih[col * 256 + korig];
        } else {
            if (k >= 256) v = W_hh[(col - 128) * 128 + (k - 256)];
        }
        WB[i] = (__bf16)v;
    }
    if (i < 512) {                             // b512
        float v;
        if (i < 256) v = b_ih[i] + b_hh[i];
        else if (i < 384) v = b_ih[i];
        else v = b_hh[i - 128];
        b512[i] = v;
    }
}

__global__ void scan1(const int* __restrict__ counts, int* __restrict__ offsets,
                      int* __restrict__ bsum, int n) {
    __shared__ int sm[256];
    int i = blockIdx.x * 256 + threadIdx.x;
    int v = (i < n) ? counts[i] : 0;
    sm[threadIdx.x] = v;
    __syncthreads();
    for (int off = 1; off < 256; off <<= 1) {
        int t = (threadIdx.x >= off) ? sm[threadIdx.x - off] : 0;
        __syncthreads();
        sm[threadIdx.x] += t;
        __syncthreads();
    }
    if (i < n) offsets[i] = sm[threadIdx.x] - v;
    if (threadIdx.x == 255) bsum[blockIdx.x] = sm[255];
}

__global__ void scan2(int* __restrict__ bsum, int nb, int* __restrict__ offsets, int n) {
    __shared__ int sm[1024];
    int t = threadIdx.x;
    int v = (t < nb) ? bsum[t] : 0;
    sm[t] = v;
    __syncthreads();
    for (int off = 1; off < 1024; off <<= 1) {
        int x = (t >= off) ? sm[t - off] : 0;
        __syncthreads();
        sm[t] += x;
        __syncthreads();
    }
    if (t < nb) bsum[t] = sm[t] - v;
    if (t == 1023) offsets[n] = sm[1023];
}

__global__ void scan3(int* __restrict__ offsets, const int* __restrict__ bsum,
                      int* __restrict__ cursor, int n) {
    int i = blockIdx.x * 256 + threadIdx.x;
    if (i < n) {
        int o = offsets[i] + bsum[blockIdx.x];
        offsets[i] = o;
        if (cursor) cursor[i] = o;
    }
}

__global__ void fill_kernel(const int* __restrict__ src, const int* __restrict__ dst,
                            const int* __restrict__ et, int* __restrict__ cursor,
                            int* __restrict__ elist) {
    int e = blockIdx.x * 256 + threadIdx.x;
    if (e >= NE) return;
    int pos = atomicAdd(&cursor[src[e] * TT + et[e]], 1);
    elist[pos] = dst[e];
}

// ================= aggregation: wave per SRC ROW (all 4 types), branchless batch-0 =====
__global__ void agg4(const int* __restrict__ offsets, const int* __restrict__ elist,
                     const __bf16* __restrict__ hbc, __bf16* __restrict__ X) {
    int row = blockIdx.x * 4 + (threadIdx.x >> 6);
    if (row >= NN) return;
    int lane = threadIdx.x & 63;
    const __bf16* hb = hbc + lane * 2;
    int ob = row * TT;
    int o0 = __builtin_amdgcn_readfirstlane(offsets[ob]);
    int o1 = __builtin_amdgcn_readfirstlane(offsets[ob + 1]);
    int o2 = __builtin_amdgcn_readfirstlane(offsets[ob + 2]);
    int o3 = __builtin_amdgcn_readfirstlane(offsets[ob + 3]);
    int o4 = __builtin_amdgcn_readfirstlane(offsets[ob + 4]);
    int begs[4] = {o0, o1, o2, o3};
    int ends[4] = {o1, o2, o3, o4};

    float ax[4] = {0.f, 0.f, 0.f, 0.f};
    float ay[4] = {0.f, 0.f, 0.f, 0.f};

    // ---- batch 0: 8 clamped gathers x 4 types, ALL issued before any accumulate ----
    bf16x2 v[4][8];
    int nb[4];
#pragma unroll
    for (int t = 0; t < 4; ++t) {
        int beg = begs[t], end = ends[t];
        nb[t] = end - beg;
        int e1 = end - 1;
        if (e1 < 0) e1 = 0;
        int idx[8];
#pragma unroll
        for (int k = 0; k < 8; ++k) {
            int p = beg + k; if (p > e1) p = e1;
            idx[k] = elist[p];
        }
#pragma unroll
        for (int k = 0; k < 8; ++k)
            v[t][k] = *(const bf16x2*)(hb + (size_t)idx[k] * DD);
    }
#pragma unroll
    for (int t = 0; t < 4; ++t) {
#pragma unroll
        for (int k = 0; k < 8; ++k) {
            float m = (nb[t] > k) ? 1.f : 0.f;
            ax[t] += m * (float)v[t][k].x;
            ay[t] += m * (float)v[t][k].y;
        }
    }

    // ---- tails (deg > 8 per type, rare) ----
#pragma unroll
    for (int t = 0; t < 4; ++t) {
        int end = ends[t];
        for (int base = begs[t] + 8; base < end; base += 8) {
            int nb2 = end - base; if (nb2 > 8) nb2 = 8;
            int e1 = end - 1;
            int idx[8];
#pragma unroll
            for (int k = 0; k < 8; ++k) {
                int p = base + k; if (p > e1) p = e1;
                idx[k] = elist[p];
            }
            bf16x2 tv[8];
#pragma unroll
            for (int k = 0; k < 8; ++k)
                tv[k] = *(const bf16x2*)(hb + (size_t)idx[k] * DD);
#pragma unroll
            for (int k = 0; k < 8; ++k) {
                float m = (nb2 > k) ? 1.f : 0.f;
                ax[t] += m * (float)tv[k].x;
                ay[t] += m * (float)tv[k].y;
            }
        }
    }

#pragma unroll
    for (int t = 0; t < 4; ++t) {
        bf16x2 o;
        o.x = (__bf16)ax[t];
        o.y = (__bf16)ay[t];
        *(bf16x2*)(X + (size_t)(ob + t) * 128 + lane * 2) = o;
    }
}

// ================= FUSED msgs GEMM + GRU GEMM (register handoff, 8-wave block) ======
__global__ __launch_bounds__(512, 4)
void msgs_gru(const __bf16* __restrict__ X, const __bf16* __restrict__ WK,
              const float* __restrict__ b_msg, const int* __restrict__ offsets,
              const __bf16* __restrict__ WBj, const float* __restrict__ b512,
              float* __restrict__ hf, __bf16* __restrict__ hbc) {
    __shared__ __bf16 Bs[2][12288];   // 48 KB total
    int tid = threadIdx.x, wave = tid >> 6, lane = tid & 63;
    int lm = lane & 15, lq = lane >> 4;
    int r0 = blockIdx.x * 128 + wave * 16;
    int arow = r0 + lm; if (arow >= NN) arow = NN - 1;

    bf16x8 a[12];   // phase-B A-fragments: [0..7]=msgs, [8..11]=h

    // ---------------- phase A: M = relu(X @ WK + deg-bias), swapped operands ----------------
    {
        const __bf16* Ap = X + (size_t)arow * 512 + lq * 8;
#pragma unroll
        for (int i = 0; i < 2; ++i) {
            int q = i * 8 + wave;
            GLDS(WK + (size_t)q * 512 + lane * 8, &Bs[0][q * 512]);
        }
        bf16x8 acur = *(const bf16x8*)(Ap);
        f32x4 acc[16] = {};
        __syncthreads();    // stage 0 landed

#pragma unroll 1
        for (int c = 0; c < 16; ++c) {
            int cur = c & 1;
            bf16x8 anext = acur;
            if (c < 15) {
                const __bf16* src = WK + (size_t)(c + 1) * 8192;
#pragma unroll
                for (int i = 0; i < 2; ++i) {
                    int q = i * 8 + wave;
                    GLDS(src + (size_t)q * 512 + lane * 8, &Bs[cur ^ 1][q * 512]);
                }
                anext = *(const bf16x8*)(Ap + (c + 1) * 32);
            }
#pragma unroll
            for (int nt = 0; nt < 16; ++nt) {
                bf16x8 b = *(const bf16x8*)&Bs[cur][((size_t)lq * 256 + nt * 16 + lm) * 8];
                // SWAPPED: A = WK frag, B = X frag  ->  acc[nt] = M^T tile
                acc[nt] = __builtin_amdgcn_mfma_f32_16x16x32_bf16(b, acur, acc[nt], 0, 0, 0);
            }
            __syncthreads();
            acur = anext;
        }
        // epilogue A (registers only): bias by row-lm degrees, relu, pack to bf16x8
        int ob2 = arow * TT;
        int q0 = offsets[ob2], q1 = offsets[ob2 + 1], q2 = offsets[ob2 + 2],
            q3 = offsets[ob2 + 3], q4 = offsets[ob2 + 4];
        float n0 = (float)(q1 - q0), n1 = (float)(q2 - q1),
              n2 = (float)(q3 - q2), n3 = (float)(q4 - q3);
#pragma unroll
        for (int c = 0; c < 8; ++c) {
#pragma unroll
            for (int e = 0; e < 8; ++e) {
                int nt = c * 2 + (e >> 2), ii = e & 3;
                int col = nt * 16 + lq * 4 + ii;
                float bias = n0 * b_msg[col] + n1 * b_msg[MM + col]
                           + n2 * b_msg[2 * MM + col] + n3 * b_msg[3 * MM + col];
                a[c][e] = (__bf16)fmaxf(acc[nt][ii] + bias, 0.f);
            }
        }
    }

    // ---------------- phase B: GRU ----------------
#pragma unroll
    for (int i = 0; i < 3; ++i) {
        int q = i * 8 + wave;
        GLDS(WBj + (size_t)q * 512 + lane * 8, &Bs[0][q * 512]);
    }
    {
        const __bf16* hp = hbc + (size_t)arow * DD + lq * 8;
#pragma unroll
        for (int c2 = 0; c2 < 4; ++c2)
            a[8 + c2] = *(const bf16x8*)(hp + c2 * 32);
    }
    __syncthreads();   // (0,0) landed

#pragma unroll 1
    for (int j = 0; j < 8; ++j) {
        const __bf16* srcj = WBj + (size_t)j * 24576;
        int d = j * 16 + lm;
        int rb = r0 + lq * 4;
        f32x4 ar = {}, az = {}, an = {}, ah = {};

        // ---- phase 2j: stage (j,1)->buf1, prefetch hold, compute half0 from buf0 ----
#pragma unroll
        for (int i = 0; i < 3; ++i) {
            int q = i * 8 + wave;
            GLDS(srcj + 12288 + (size_t)q * 512 + lane * 8, &Bs[1][q * 512]);
        }
        float h0 = hf[(size_t)(rb + 0 < NN ? rb + 0 : NN - 1) * DD + d];
        float h1 = hf[(size_t)(rb + 1 < NN ? rb + 1 : NN - 1) * DD + d];
        float h2 = hf[(size_t)(rb + 2 < NN ? rb + 2 : NN - 1) * DD + d];
        float h3 = hf[(size_t)(rb + 3 < NN ? rb + 3 : NN - 1) * DD + d];
#pragma unroll
        for (int cc = 0; cc < 6; ++cc) {
            const __bf16* Bp = &Bs[0][(cc * 4 + lq) * 512 + lm * 8];
            bf16x8 br = *(const bf16x8*)(Bp);
            bf16x8 bz = *(const bf16x8*)(Bp + 128);
            bf16x8 bn = *(const bf16x8*)(Bp + 256);
            bf16x8 bh = *(const bf16x8*)(Bp + 384);
            ar = __builtin_amdgcn_mfma_f32_16x16x32_bf16(a[cc], br, ar, 0, 0, 0);
            az = __builtin_amdgcn_mfma_f32_16x16x32_bf16(a[cc], bz, az, 0, 0, 0);
            an = __builtin_amdgcn_mfma_f32_16x16x32_bf16(a[cc], bn, an, 0, 0, 0);
            ah = __builtin_amdgcn_mfma_f32_16x16x32_bf16(a[cc], bh, ah, 0, 0, 0);
        }
        __syncthreads();   // (j,1) landed; all waves done with buf0

        // ---- phase 2j+1: stage (j+1,0)->buf0 (if any), compute half1 from buf1 ----
        if (j < 7) {
#pragma unroll
            for (int i = 0; i < 3; ++i) {
                int q = i * 8 + wave;
                GLDS(srcj + 24576 + (size_t)q * 512 + lane * 8, &Bs[0][q * 512]);
            }
        }
#pragma unroll
        for (int cc = 0; cc < 6; ++cc) {
            const __bf16* Bp = &Bs[1][(cc * 4 + lq) * 512 + lm * 8];
            bf16x8 br = *(const bf16x8*)(Bp);
            bf16x8 bz = *(const bf16x8*)(Bp + 128);
            bf16x8 bn = *(const bf16x8*)(Bp + 256);
            bf16x8 bh = *(const bf16x8*)(Bp + 384);
            ar = __builtin_amdgcn_mfma_f32_16x16x32_bf16(a[6 + cc], br, ar, 0, 0, 0);
            az = __builtin_amdgcn_mfma_f32_16x16x32_bf16(a[6 + cc], bz, az, 0, 0, 0);
            an = __builtin_amdgcn_mfma_f32_16x16x32_bf16(a[6 + cc], bn, an, 0, 0, 0);
            ah = __builtin_amdgcn_mfma_f32_16x16x32_bf16(a[6 + cc], bh, ah, 0, 0, 0);
        }
        // ---- epilogue for j (registers + global only) ----
        float cbr = b512[d], cbz = b512[128 + d], cbn = b512[256 + d], cbh = b512[384 + d];
        float hv[4] = {h0, h1, h2, h3};
#pragma unroll
        for (int i = 0; i < 4; ++i) {
            int row = rb + i;
            if (row >= NN) continue;
            float pr  = ar[i] + cbr;
            float pz  = az[i] + cbz;
            float pin = an[i] + cbn;
            float phn = ah[i] + cbh;
            float r = fast_sigmoid(pr);
            float z = fast_sigmoid(pz);
            float nv = fast_tanh(pin + r * phn);
            float hnew = (1.f - z) * nv + z * hv[i];
            hf[(size_t)row * DD + d] = hnew;
            hbc[(size_t)row * DD + d] = (__bf16)hnew;
        }
        __syncthreads();   // (j+1,0) landed; all waves done with buf1
    }
}

// ================= readout: attn + segsum + W_g projection in ONE kernel =================
// Block g: chunked over its nodes. Stage 1: thread t computes attn for node c0+t
// into LDS. Stage 2: 128 threads accumulate a*hf into per-d partials. Then W_g.
__global__ void segsum_readout(const int* __restrict__ goff, const float* __restrict__ hf,
                               const float* __restrict__ w_gate, const float* __restrict__ b_gate,
                               const float* __restrict__ W_g, const float* __restrict__ b_g,
                               float* __restrict__ hgraph) {
    __shared__ float sgs[DD];
    __shared__ float asums;
    __shared__ float wg[DD];
    __shared__ float at[128];
    int g = blockIdx.x;
    int d = threadIdx.x;
    wg[d] = w_gate[d];
    float bg = b_gate[0];
    int beg = goff[g], end = goff[g + 1];
    float s0 = 0.f, s1 = 0.f, s2 = 0.f, s3 = 0.f, asum = 0.f;
    for (int c0 = beg; c0 < end; c0 += 128) {
        int cnt = end - c0; if (cnt > 128) cnt = 128;
        __syncthreads();           // wg ready (1st iter) / at consumed (later iters)
        if (d < cnt) {
            const float* hp = hf + (size_t)(c0 + d) * DD;
            float acc = 0.f;
            for (int k = 0; k < DD; k += 4) {
                acc += hp[k] * wg[k] + hp[k + 1] * wg[k + 1]
                     + hp[k + 2] * wg[k + 2] + hp[k + 3] * wg[k + 3];
            }
            at[d] = 1.f / (1.f + expf(-(acc + bg)));
        }
        __syncthreads();           // at ready
        int i = 0;
        for (; i + 3 < cnt; i += 4) {
            float a0 = at[i], a1 = at[i + 1], a2 = at[i + 2], a3 = at[i + 3];
            float v0 = hf[(size_t)(c0 + i) * DD + d];
            float v1 = hf[(size_t)(c0 + i + 1) * DD + d];
            float v2 = hf[(size_t)(c0 + i + 2) * DD + d];
            float v3 = hf[(size_t)(c0 + i + 3) * DD + d];
            s0 += a0 * v0; s1 += a1 * v1; s2 += a2 * v2; s3 += a3 * v3;
            if (d == 0) asum += a0 + a1 + a2 + a3;
        }
        for (; i < cnt; ++i) {
            float a = at[i];
            s0 += a * hf[(size_t)(c0 + i) * DD + d];
            if (d == 0) asum += a;
        }
    }
    sgs[d] = s0 + s1 + s2 + s3;
    if (d == 0) asums = asum;
    __syncthreads();
    float av = asums;
    float o0 = av * b_g[d];
    float o1 = av * b_g[d + 128];
    for (int k = 0; k < DD; ++k) {
        float sv = sgs[k];
        o0 += sv * W_g[k * GHID + d];
        o1 += sv * W_g[k * GHID + d + 128];
    }
    hgraph[g * GHID + d] = o0;
    hgraph[g * GHID + d + 128] = o1;
}

// ================= launch =================
extern "C" void kernel_launch(void* const* d_in, const int* in_sizes, int n_in,
                              void* d_out, int out_size, void* d_ws, size_t ws_size,
                              hipStream_t stream) {
    const int*   node_types = (const int*)d_in[0];
    const int*   edge_src   = (const int*)d_in[1];
    const int*   edge_dst   = (const int*)d_in[2];
    const int*   edge_type  = (const int*)d_in[3];
    const int*   node2graph = (const int*)d_in[4];
    const float* emb        = (const float*)d_in[5];
    const float* W_msg      = (const float*)d_in[6];
    const float* b_msg      = (const float*)d_in[7];
    const float* W_ih       = (const float*)d_in[8];
    const float* W_hh       = (const float*)d_in[9];
    const float* b_ih       = (const float*)d_in[10];
    const float* b_hh       = (const float*)d_in[11];
    const float* w_gate     = (const float*)d_in[12];
    const float* b_gate     = (const float*)d_in[13];
    const float* W_g        = (const float*)d_in[14];
    const float* b_g        = (const float*)d_in[15];

    float* hf     = (float*)d_out;
    float* hgraph = hf + (size_t)NN * DD;

    char* ws = (char*)d_ws;
    size_t off = 0;
    auto alloc = [&](size_t bytes) -> char* {
        char* p = ws + off;
        off += (bytes + 255) & ~(size_t)255;
        return p;
    };
    __bf16* X       = (__bf16*)alloc((size_t)NN * 512 * 2);   // 51.2 MB
    __bf16* hbc     = (__bf16*)alloc((size_t)NN * DD * 2);    // 12.8 MB compact h
    __bf16* WK      = (__bf16*)alloc((size_t)16 * 4 * 256 * 8 * 2);
    __bf16* WB      = (__bf16*)alloc((size_t)12 * 4 * 512 * 8 * 2);
    float*  b512    = (float*)alloc(512 * 4);
    int*    counts  = (int*)alloc((size_t)(NKEY + 1) * 4);
    int*    offsets = (int*)alloc((size_t)(NKEY + 1) * 4);
    int*    cursor  = (int*)alloc((size_t)(NKEY + 1) * 4);
    int*    bsum    = (int*)alloc((size_t)1024 * 4);
    int*    elist   = (int*)alloc((size_t)NE * 4);
    int*    goff    = (int*)alloc((size_t)(NG + 1) * 4);

    hipMemsetAsync(counts, 0, (NKEY + 1) * 4, stream);

    build_all<<<(NN * DD + 255) / 256, 256, 0, stream>>>(
        W_msg, W_ih, W_hh, b_ih, b_hh, node_types, emb,
        edge_src, edge_type, node2graph,
        WK, WB, b512, hf, hbc, counts, goff);

    int nbE = (NKEY + 255) / 256;
    scan1<<<nbE, 256, 0, stream>>>(counts, offsets, bsum, NKEY);
    scan2<<<1, 1024, 0, stream>>>(bsum, nbE, offsets, NKEY);
    scan3<<<nbE, 256, 0, stream>>>(offsets, bsum, cursor, NKEY);
    fill_kernel<<<(NE + 255) / 256, 256, 0, stream>>>(edge_src, edge_dst, edge_type, cursor, elist);

    int rt2 = (NN + 127) / 128;  // 391
    for (int p = 0; p < NPASS; ++p) {
        agg4<<<(NN + 3) / 4, 256, 0, stream>>>(offsets, elist, hbc, X);
        msgs_gru<<<rt2, 512, 0, stream>>>(X, WK, b_msg, offsets, WB, b512, hf, hbc);
    }

    segsum_readout<<<NG, DD, 0, stream>>>(goff, hf, w_gate, b_gate, W_g, b_g, hgraph);
}